// Round 7
// baseline (245.429 us; speedup 1.0000x reference)
//
#include <hip/hip_runtime.h>

// AttnBlock on MI355X — round 7: m201-style 256x256 8-wave core (full-tile
// prefetch, boundary-only vmcnt(8)) for qk/w/se/pvproj; R5 fusion retained.

typedef __bf16 bf16;
typedef __attribute__((ext_vector_type(8))) __bf16 bf16x8;
typedef __attribute__((ext_vector_type(4))) __bf16 bf16x4;
typedef __attribute__((ext_vector_type(4))) float f32x4;

#define CC 512
#define NN 4096
#define BK 64
// 512^-0.5 * log2(e): folded into qT so se uses exp2f directly
#define SCALE_L2E 0.06376237870903338f

__device__ __forceinline__ void gload16(const bf16* g, bf16* l) {
    __builtin_amdgcn_global_load_lds(
        (const __attribute__((address_space(1))) unsigned int*)g,
        (__attribute__((address_space(3))) unsigned int*)l, 16, 0, 0);
}

// ---------------------------------------------------------------------------
// core256: 256x256 block tile, 512 threads = 8 waves (2m x 4n), wave tile
// 128x64 (8x4 frags of 16x16x32). LDS 128KB: A[2][256][64] + B[2][256][64].
// Full-tile staging (8 gload/thread), st-16x32 XOR swizzle (swizzled global
// source, linear LDS dest, swizzled read col). Pipeline: stage t+2 after the
// tile-t read barrier; vmcnt(8) waits only tile t+1's loads (issued a full
// tile earlier -> latency hidden). No mid-tile barriers.
// A: row-major [M,K] (lda). B: [N,K] row-major (ldb).
// ---------------------------------------------------------------------------
__device__ __forceinline__ void core256(
    const bf16* __restrict__ A, int lda,
    const bf16* __restrict__ B, int ldb,
    int m0, int n0, int kBeg, int nt, f32x4 acc[8][4])
{
    __shared__ __align__(16) bf16 lsA[2][256][64];
    __shared__ __align__(16) bf16 lsB[2][256][64];

    const int t    = threadIdx.x;          // 0..511
    const int lane = t & 63;
    const int wid  = t >> 6;               // 0..7
    const int wr   = wid >> 2;             // 0..1  (m half: 128 rows)
    const int wc   = wid & 3;              // 0..3  (n quarter: 64 cols)
    const int fr   = lane & 15;
    const int kq   = lane >> 4;            // 0..3
    const int cs0  = ((kq)     ^ (fr & 7)) * 8;
    const int cs1  = ((kq + 4) ^ (fr & 7)) * 8;

    // staging geometry: thread covers rows r0+64j (j=0..3 A, j=0..3 B)
    const int r0  = t >> 3;                // 0..63
    const int blk = (t & 7) ^ (r0 & 7);    // swizzled source 16B block
    const int dc  = (t & 7) * 8;           // linear LDS dest col (elems)
    const bf16* Abase = A + (size_t)(m0 + r0) * lda + kBeg + blk * 8;
    const bf16* Bbase = B + (size_t)(n0 + r0) * ldb + kBeg + blk * 8;

    auto STAGE = [&](int db, int kk) {
        const bf16* Ag = Abase + kk;
        const bf16* Bg = Bbase + kk;
        bf16* la = &lsA[db][r0][dc];
        bf16* lb = &lsB[db][r0][dc];
        #pragma unroll
        for (int j = 0; j < 4; ++j)
            gload16(Ag + (size_t)(64 * j) * lda, la + j * 64 * 64);
        #pragma unroll
        for (int j = 0; j < 4; ++j)
            gload16(Bg + (size_t)(64 * j) * ldb, lb + j * 64 * 64);
    };

    STAGE(0, 0);
    asm volatile("s_waitcnt vmcnt(0)" ::: "memory");
    __builtin_amdgcn_s_barrier();
    STAGE(1, BK);

    const int arow = wr * 128 + fr;
    const int brow = wc * 64 + fr;

    for (int t_ = 0; t_ < nt; ++t_) {
        const int db = t_ & 1;
        const bf16 (*Ab)[64] = lsA[db];
        const bf16 (*Bb)[64] = lsB[db];
        #pragma unroll
        for (int kh = 0; kh < 2; ++kh) {
            const int cs = kh ? cs1 : cs0;
            bf16x8 bgr[4];
            #pragma unroll
            for (int g = 0; g < 4; ++g)
                bgr[g] = *(const bf16x8*)&Bb[brow + g * 16][cs];
            #pragma unroll
            for (int mh = 0; mh < 2; ++mh) {
                bf16x8 afr[4];
                #pragma unroll
                for (int f = 0; f < 4; ++f)
                    afr[f] = *(const bf16x8*)&Ab[arow + mh * 64 + f * 16][cs];
                #pragma unroll
                for (int f = 0; f < 4; ++f)
                    #pragma unroll
                    for (int g = 0; g < 4; ++g)
                        acc[mh * 4 + f][g] = __builtin_amdgcn_mfma_f32_16x16x32_bf16(
                            afr[f], bgr[g], acc[mh * 4 + f][g], 0, 0, 0);
            }
        }
        // all waves done reading buf db (MFMA operand waits ensured lgkmcnt)
        __builtin_amdgcn_s_barrier();
        if (t_ + 2 < nt) {
            STAGE(db, (t_ + 2) * BK);              // overwrite freed buffer
            asm volatile("s_waitcnt vmcnt(8)" ::: "memory");  // t+1 landed
        } else {
            asm volatile("s_waitcnt vmcnt(0)" ::: "memory");
        }
        __builtin_amdgcn_s_barrier();              // t+1 visible to all waves
    }
}

// ---------------------------------------------------------------------------
// Legacy 4-wave 128x128 double-buffered core (tiny fw GEMM only)
// ---------------------------------------------------------------------------
__device__ __forceinline__ void gemm_core(
    const bf16* __restrict__ A, int lda,
    const bf16* __restrict__ B, int ldb,
    int kBeg, int kEnd, int m0, int n0, f32x4 acc[4][4])
{
    __shared__ __align__(16) bf16 Als[2][128][BK];
    __shared__ __align__(16) bf16 Bls[2][128][BK];
    const int t    = threadIdx.x;
    const int lane = t & 63;
    const int wid  = t >> 6;
    const int wm   = (wid >> 1) * 64;
    const int wn   = (wid & 1) * 64;
    const int fr   = lane & 15;
    const int kq   = lane >> 4;
    const int r_   = t >> 3;
    const int cbs  = (t & 7) ^ (r_ & 7);
    const int dcol = (t & 7) * 8;
    const int cs0  = ((kq)     ^ (fr & 7)) * 8;
    const int cs1  = ((kq + 4) ^ (fr & 7)) * 8;

    const bf16* Ab = A + (size_t)(m0 + r_) * lda + cbs * 8;
    const bf16* Bb = B + (size_t)(n0 + r_) * ldb + cbs * 8;

#define STAGE_G(bufi, kk) do {                                              \
        _Pragma("unroll")                                                   \
        for (int i = 0; i < 4; ++i)                                         \
            gload16(Ab + (kk) + (size_t)(i * 32) * lda,                     \
                    &Als[bufi][i * 32 + r_][dcol]);                         \
        _Pragma("unroll")                                                   \
        for (int i = 0; i < 4; ++i)                                         \
            gload16(Bb + (kk) + (size_t)(i * 32) * ldb,                     \
                    &Bls[bufi][i * 32 + r_][dcol]);                         \
    } while (0)

    int cur = 0;
    STAGE_G(0, kBeg);
    __syncthreads();
    for (int k0 = kBeg; k0 < kEnd; k0 += BK) {
        if (k0 + BK < kEnd) STAGE_G(cur ^ 1, k0 + BK);
        #pragma unroll
        for (int h = 0; h < 2; ++h) {
            const int cs = h ? cs1 : cs0;
            bf16x8 af[4], bg[4];
            #pragma unroll
            for (int f = 0; f < 4; ++f) {
                af[f] = *(const bf16x8*)&Als[cur][wm + f * 16 + fr][cs];
                bg[f] = *(const bf16x8*)&Bls[cur][wn + f * 16 + fr][cs];
            }
            #pragma unroll
            for (int fm = 0; fm < 4; ++fm)
                #pragma unroll
                for (int fn = 0; fn < 4; ++fn)
                    acc[fm][fn] = __builtin_amdgcn_mfma_f32_16x16x32_bf16(
                        af[fm], bg[fn], acc[fm][fn], 0, 0, 0);
        }
        __syncthreads();
        cur ^= 1;
    }
#undef STAGE_G
}

// ---------------------------------------------------------------------------
// Prep kernels
// ---------------------------------------------------------------------------
__global__ __launch_bounds__(256) void convert_w_kernel(
    const float* __restrict__ qw, const float* __restrict__ kw,
    const float* __restrict__ pw, bf16* __restrict__ dst)
{
    const int which = blockIdx.y;
    const float* src = which == 0 ? qw : which == 1 ? kw : pw;
    const int slot  = which == 2 ? 3 : which;
    bf16* d = dst + (size_t)slot * (CC * CC);
    const int f4 = blockIdx.x * 256 + threadIdx.x;
    float4 v = ((const float4*)src)[f4];
    bf16x4 o;
    o[0] = (bf16)v.x; o[1] = (bf16)v.y; o[2] = (bf16)v.z; o[3] = (bf16)v.w;
    ((bf16x4*)d)[f4] = o;
}

// vwT[k][c] = vw[c][k]
__global__ __launch_bounds__(256) void vwT_kernel(
    const float* __restrict__ vw, bf16* __restrict__ vwT)
{
    const int k0 = blockIdx.x * 64;
    const int c0 = blockIdx.y * 64;
    const int t  = threadIdx.x;
    const int tk = t & 15, tc = t >> 4;
    float o[4][4];
    #pragma unroll
    for (int j = 0; j < 4; ++j) {
        const int c = c0 + tc * 4 + j;
        float4 v = *(const float4*)(vw + (size_t)c * CC + k0 + tk * 4);
        o[j][0] = v.x; o[j][1] = v.y; o[j][2] = v.z; o[j][3] = v.w;
    }
    #pragma unroll
    for (int i = 0; i < 4; ++i) {
        bf16x4 w4;
        w4[0] = (bf16)o[0][i]; w4[1] = (bf16)o[1][i];
        w4[2] = (bf16)o[2][i]; w4[3] = (bf16)o[3][i];
        *(bf16x4*)(vwT + (size_t)(k0 + tk * 4 + i) * CC + c0 + tc * 4) = w4;
    }
}

// wb[o] = sum_c pw[o][c] * vb[c]
__global__ __launch_bounds__(256) void wb_kernel(
    const float* __restrict__ pw, const float* __restrict__ vb,
    float* __restrict__ wb)
{
    const int o = blockIdx.x * 256 + threadIdx.x;
    const float4* row = (const float4*)(pw + (size_t)o * CC);
    const float4* v4  = (const float4*)vb;
    float s = 0.f;
    #pragma unroll 4
    for (int i = 0; i < 128; ++i) {
        float4 a = row[i], b = v4[i];
        s += a.x * b.x + a.y * b.y + a.z * b.z + a.w * b.w;
    }
    wb[o] = s;
}

__global__ __launch_bounds__(256) void gn_stats_kernel(
    const float* __restrict__ x, float* __restrict__ mr)
{
    const int bg = blockIdx.x;
    const float4* base = (const float4*)(x + (size_t)bg * 16 * NN);
    const int t = threadIdx.x;
    float s = 0.f, sq = 0.f;
    #pragma unroll 4
    for (int i = 0; i < 64; ++i) {
        float4 v = base[i * 256 + t];
        s  += v.x + v.y + v.z + v.w;
        sq += v.x * v.x + v.y * v.y + v.z * v.z + v.w * v.w;
    }
    #pragma unroll
    for (int o = 32; o > 0; o >>= 1) { s += __shfl_xor(s, o); sq += __shfl_xor(sq, o); }
    __shared__ float rs[4], rq[4];
    const int lane = t & 63, wid = t >> 6;
    if (lane == 0) { rs[wid] = s; rq[wid] = sq; }
    __syncthreads();
    if (t == 0) {
        float S = rs[0] + rs[1] + rs[2] + rs[3];
        float Q = rq[0] + rq[1] + rq[2] + rq[3];
        const float invn = 1.f / 65536.f;
        float mean = S * invn;
        float var  = Q * invn - mean * mean;
        mr[bg * 2]     = mean;
        mr[bg * 2 + 1] = rsqrtf(var + 1e-6f);
    }
}

// GN apply + transpose: x[b,c,n] fp32 -> hT[b,n,c] bf16
__global__ __launch_bounds__(256) void gn_apply_T_kernel(
    const float* __restrict__ x, const float* __restrict__ gw,
    const float* __restrict__ gb, const float* __restrict__ mr,
    bf16* __restrict__ hT)
{
    const int b  = blockIdx.z;
    const int n0 = blockIdx.x * 64;
    const int c0 = blockIdx.y * 64;
    const int t  = threadIdx.x;
    const int tn = t & 15, tc = t >> 4;
    float o[4][4];
    #pragma unroll
    for (int j = 0; j < 4; ++j) {
        const int c = c0 + tc * 4 + j;
        const int bg = b * 32 + (c >> 4);
        const float mean = mr[bg * 2], rstd = mr[bg * 2 + 1];
        const float w  = gw[c] * rstd;
        const float bb = gb[c] - mean * w;
        float4 v = *(const float4*)(x + ((size_t)(b * CC + c)) * NN + n0 + tn * 4);
        o[j][0] = v.x * w + bb; o[j][1] = v.y * w + bb;
        o[j][2] = v.z * w + bb; o[j][3] = v.w * w + bb;
    }
    bf16* dst = hT + (size_t)b * (size_t)NN * CC;
    #pragma unroll
    for (int i = 0; i < 4; ++i) {
        bf16x4 w4;
        w4[0] = (bf16)o[0][i]; w4[1] = (bf16)o[1][i];
        w4[2] = (bf16)o[2][i]; w4[3] = (bf16)o[3][i];
        *(bf16x4*)(dst + (size_t)(n0 + tn * 4 + i) * CC + c0 + tc * 4) = w4;
    }
}

// ---------------------------------------------------------------------------
// GEMM kernels
// ---------------------------------------------------------------------------
// fw[o][k] = sum_c pw[o][c] * vwT[k][c]  (legacy core)
__global__ __launch_bounds__(256) void fw_gemm_kernel(
    const bf16* __restrict__ pwb, const bf16* __restrict__ vwT,
    bf16* __restrict__ fw)
{
    const int m0 = blockIdx.y * 128, n0 = blockIdx.x * 128;
    f32x4 acc[4][4] = {};
    gemm_core(pwb, CC, vwT, CC, 0, CC, m0, n0, acc);
    const int lane = threadIdx.x & 63, wid = threadIdx.x >> 6;
    const int wm = (wid >> 1) * 64, wn = (wid & 1) * 64;
    const int cf = lane & 15, rb = (lane >> 4) * 4;
    #pragma unroll
    for (int fm = 0; fm < 4; ++fm)
      #pragma unroll
      for (int fn = 0; fn < 4; ++fn)
        #pragma unroll
        for (int r = 0; r < 4; ++r)
            fw[(size_t)(m0 + wm + fm * 16 + rb + r) * CC
               + (n0 + wn + fn * 16 + cf)] = (bf16)acc[fm][fn][r];
}

// Merged qk + w GEMMs. x-block 0..95: role = x/32 (0=q,1=k,2=w), s = x%32.
// q/k: out[i][o] = hT[i,:].w[o,:] + bias (q *= SCALE_L2E), out stride CC.
// w:   Wt[o][j]  = fw[o,:].hT[j,:],                        out stride NN.
__global__ __launch_bounds__(512, 2) void qkw_gemm_kernel(
    const bf16* __restrict__ hT, const bf16* __restrict__ wbf,
    const bf16* __restrict__ fw,
    const float* __restrict__ qb, const float* __restrict__ kb,
    bf16* __restrict__ qT, bf16* __restrict__ kT, bf16* __restrict__ Wt)
{
    const int b = blockIdx.z;
    const size_t CN = (size_t)CC * NN;
    const int x = blockIdx.x;
    const int role = x >> 5, s = x & 31;
    const bf16* hT_b = hT + (size_t)b * CN;

    const bf16* A; int lda; const bf16* B; int ldb;
    int m0, n0, ldo; bf16* outp; const float* bias;
    if (role < 2) {
        A = hT_b; lda = CC;
        B = wbf + (size_t)role * CC * CC; ldb = CC;
        m0 = (s >> 1) * 256; n0 = (s & 1) * 256;
        outp = (role ? kT : qT) + (size_t)b * CN; ldo = CC;
        bias = role ? kb : qb;
    } else {
        A = fw; lda = CC;
        B = hT_b; ldb = CC;
        m0 = (s >> 4) * 256; n0 = (s & 15) * 256;
        outp = Wt + (size_t)b * CN; ldo = NN;
        bias = nullptr;
    }
    f32x4 acc[8][4] = {};
    core256(A, lda, B, ldb, m0, n0, 0, CC / BK, acc);

    const int lane = threadIdx.x & 63, wid = threadIdx.x >> 6;
    const int wr = wid >> 2, wc = wid & 3;
    const int cf = lane & 15, rb = (lane >> 4) * 4;
    #pragma unroll
    for (int fm = 0; fm < 8; ++fm)
      #pragma unroll
      for (int g = 0; g < 4; ++g) {
          const int col = n0 + wc * 64 + g * 16 + cf;
          const float bv = (role < 2) ? bias[col] : 0.f;
          #pragma unroll
          for (int r = 0; r < 4; ++r) {
              const int row = m0 + wr * 128 + fm * 16 + rb + r;
              float val = acc[fm][g][r] + bv;
              if (role == 0) val *= SCALE_L2E;
              outp[(size_t)row * ldo + col] = (bf16)val;
          }
      }
}

// E[b][i][j] = exp2(qT[i,:].kT[j,:]); rowsum[b][i] += partials (atomic)
__global__ __launch_bounds__(512, 2) void se_gemm_kernel(
    const bf16* __restrict__ qT, const bf16* __restrict__ kT,
    bf16* __restrict__ E, float* __restrict__ rowsum)
{
    const int b = blockIdx.z;
    const size_t CN = (size_t)CC * NN;
    const bf16* qT_b = qT + (size_t)b * CN;
    const bf16* kT_b = kT + (size_t)b * CN;
    bf16* E_b = E + (size_t)b * NN * NN;
    float* rs_b = rowsum + (size_t)b * NN;
    const int m0 = blockIdx.y * 256, n0 = blockIdx.x * 256;
    f32x4 acc[8][4] = {};
    core256(qT_b, CC, kT_b, CC, m0, n0, 0, CC / BK, acc);

    const int lane = threadIdx.x & 63, wid = threadIdx.x >> 6;
    const int wr = wid >> 2, wc = wid & 3;
    const int cf = lane & 15, rb = (lane >> 4) * 4;
    #pragma unroll
    for (int fm = 0; fm < 8; ++fm)
      #pragma unroll
      for (int g = 0; g < 4; ++g)
        #pragma unroll
        for (int r = 0; r < 4; ++r) {
            float e = exp2f(fminf(acc[fm][g][r], 86.f));
            acc[fm][g][r] = e;
            E_b[(size_t)(m0 + wr * 128 + fm * 16 + rb + r) * NN
                + (n0 + wc * 64 + g * 16 + cf)] = (bf16)e;
        }
    #pragma unroll
    for (int fm = 0; fm < 8; ++fm)
      #pragma unroll
      for (int r = 0; r < 4; ++r) {
          float s = acc[fm][0][r] + acc[fm][1][r] + acc[fm][2][r] + acc[fm][3][r];
          s += __shfl_xor(s, 1); s += __shfl_xor(s, 2);
          s += __shfl_xor(s, 4); s += __shfl_xor(s, 8);
          if (cf == 0)
              atomicAdd(&rs_b[m0 + wr * 128 + fm * 16 + rb + r], s);
      }
}

// S32[b][o][n] += sum_{j in slice} Wt[o][j] * E[n][j]   (split-K=4)
__global__ __launch_bounds__(512, 2) void pvproj_kernel(
    const bf16* __restrict__ Wt, const bf16* __restrict__ E,
    float* __restrict__ S32)
{
    const int b  = blockIdx.z >> 2;
    const int ks = blockIdx.z & 3;
    const size_t CN = (size_t)CC * NN;
    const int m0 = blockIdx.y * 256, n0 = blockIdx.x * 256;
    f32x4 acc[8][4] = {};
    core256(Wt + (size_t)b * CN, NN, E + (size_t)b * NN * NN, NN,
            m0, n0, ks * 1024, 16, acc);
    float* S_b = S32 + (size_t)b * CN;
    const int lane = threadIdx.x & 63, wid = threadIdx.x >> 6;
    const int wr = wid >> 2, wc = wid & 3;
    const int cf = lane & 15, rb = (lane >> 4) * 4;
    #pragma unroll
    for (int fm = 0; fm < 8; ++fm)
      #pragma unroll
      for (int g = 0; g < 4; ++g) {
          const int col = n0 + wc * 64 + g * 16 + cf;
          #pragma unroll
          for (int r = 0; r < 4; ++r) {
              const int row = m0 + wr * 128 + fm * 16 + rb + r;
              atomicAdd(&S_b[(size_t)row * NN + col], acc[fm][g][r]);
          }
      }
}

// rsinv[i] = 1 / rowsum[i]
__global__ __launch_bounds__(256) void rsinv_kernel(
    const float* __restrict__ rowsum, float* __restrict__ rsinv)
{
    const int i = blockIdx.x * 256 + threadIdx.x;
    rsinv[i] = 1.f / rowsum[i];
}

// out[b][o][n] = S32[b][o][n]*rsinv[b][n] + wb[o] + pb[o] + x[b][o][n]
__global__ __launch_bounds__(256) void pvfin_kernel(
    const float* __restrict__ S32, const float* __restrict__ rsinv,
    const float* __restrict__ wb, const float* __restrict__ pb,
    const float* __restrict__ x, float* __restrict__ outp)
{
    const size_t f4 = (size_t)blockIdx.x * 256 + threadIdx.x;
    const size_t e  = f4 * 4;
    const int n = (int)(e & (NN - 1));
    const int o = (int)((e >> 12) & (CC - 1));
    const int b = (int)(e >> 21);
    float4 sv = ((const float4*)S32)[f4];
    float4 iv = *(const float4*)(rsinv + (size_t)b * NN + n);
    float4 xv = ((const float4*)x)[f4];
    const float bias = wb[o] + pb[o];
    float4 ov;
    ov.x = sv.x * iv.x + bias + xv.x;
    ov.y = sv.y * iv.y + bias + xv.y;
    ov.z = sv.z * iv.z + bias + xv.z;
    ov.w = sv.w * iv.w + bias + xv.w;
    ((float4*)outp)[f4] = ov;
}

// ---------------------------------------------------------------------------
extern "C" void kernel_launch(void* const* d_in, const int* in_sizes, int n_in,
                              void* d_out, int out_size, void* d_ws, size_t ws_size,
                              hipStream_t stream)
{
    const float* x   = (const float*)d_in[0];
    const float* gnw = (const float*)d_in[1];
    const float* gnb = (const float*)d_in[2];
    const float* qw  = (const float*)d_in[3];
    const float* qb  = (const float*)d_in[4];
    const float* kw  = (const float*)d_in[5];
    const float* kb  = (const float*)d_in[6];
    const float* vw  = (const float*)d_in[7];
    const float* vb  = (const float*)d_in[8];
    const float* pw  = (const float*)d_in[9];
    const float* pb  = (const float*)d_in[10];
    float* outp = (float*)d_out;

    char* ws = (char*)d_ws;
    size_t off = 0;
    auto alloc = [&](size_t bytes) -> char* {
        char* p = ws + off;
        off = (off + bytes + 255) & ~(size_t)255;
        return p;
    };
    const size_t CN = (size_t)CC * NN;
    bf16*  wbf  = (bf16*)alloc(4 * (size_t)CC * CC * sizeof(bf16));   // q,k,vwT,pw
    bf16*  hT   = (bf16*)alloc(2 * CN * sizeof(bf16));                // 8MB
    bf16*  qT   = (bf16*)alloc(2 * CN * sizeof(bf16));                // 8MB
    bf16*  kT   = (bf16*)alloc(2 * CN * sizeof(bf16));                // 8MB
    bf16*  fw   = (bf16*)alloc((size_t)CC * CC * sizeof(bf16));       // 0.5MB
    bf16*  Wt   = (bf16*)alloc(2 * CN * sizeof(bf16));                // 8MB
    bf16*  E    = (bf16*)alloc(2 * (size_t)NN * NN * sizeof(bf16));   // 64MB
    float* rowsum = (float*)alloc(2 * NN * sizeof(float));            // 32KB
    float* rsinv  = (float*)alloc(2 * NN * sizeof(float));            // 32KB
    float* wb   = (float*)alloc(CC * sizeof(float));
    float* mr   = (float*)alloc(64 * 2 * sizeof(float));
    // S32 (16MB fp32) aliased onto qT..kT (dead after se_gemm)
    float* S32  = (float*)qT;

    bf16* vwT = wbf + 2 * (size_t)CC * CC;
    bf16* pwb = wbf + 3 * (size_t)CC * CC;

    convert_w_kernel<<<dim3(256, 3), 256, 0, stream>>>(qw, kw, pw, wbf);
    vwT_kernel<<<dim3(8, 8), 256, 0, stream>>>(vw, vwT);
    wb_kernel<<<2, 256, 0, stream>>>(pw, vb, wb);
    gn_stats_kernel<<<64, 256, 0, stream>>>(x, mr);
    gn_apply_T_kernel<<<dim3(NN / 64, CC / 64, 2), 256, 0, stream>>>(
        x, gnw, gnb, mr, hT);
    hipMemsetAsync(rowsum, 0, 2 * NN * sizeof(float), stream);

    fw_gemm_kernel<<<dim3(4, 4), 256, 0, stream>>>(pwb, vwT, fw);
    qkw_gemm_kernel<<<dim3(96, 1, 2), 512, 0, stream>>>(
        hT, wbf, fw, qb, kb, qT, kT, Wt);

    se_gemm_kernel<<<dim3(16, 16, 2), 512, 0, stream>>>(qT, kT, E, rowsum);

    rsinv_kernel<<<32, 256, 0, stream>>>(rowsum, rsinv);
    hipMemsetAsync(S32, 0, 2 * CN * sizeof(float), stream);
    pvproj_kernel<<<dim3(16, 2, 8), 512, 0, stream>>>(Wt, E, S32);

    pvfin_kernel<<<4096, 256, 0, stream>>>(S32, rsinv, wb, pb, x, outp);
}

// Round 8
// 222.745 us; speedup vs baseline: 1.1018x; 1.1018x over previous
//
#include <hip/hip_runtime.h>

// AttnBlock on MI355X — round 8: R5 pipeline, but ALL large GEMMs on the
// proven 3-blocks/CU 64x128 core (within-session best: ~690 TF effective).

typedef __bf16 bf16;
typedef __attribute__((ext_vector_type(8))) __bf16 bf16x8;
typedef __attribute__((ext_vector_type(4))) __bf16 bf16x4;
typedef __attribute__((ext_vector_type(4))) float f32x4;

#define CC 512
#define NN 4096
#define BM 128
#define BN 128
#define BK 64
// 512^-0.5 * log2(e): folded into qT so se uses exp2f directly
#define SCALE_L2E 0.06376237870903338f

__device__ __forceinline__ void gload16(const bf16* g, bf16* l) {
    __builtin_amdgcn_global_load_lds(
        (const __attribute__((address_space(1))) unsigned int*)g,
        (__attribute__((address_space(3))) unsigned int*)l, 16, 0, 0);
}

// ---------------------------------------------------------------------------
// 128x128 MFMA GEMM core (4 waves), 2-phase double-buffered (fw only).
// ---------------------------------------------------------------------------
__device__ __forceinline__ void gemm_core(
    const bf16* __restrict__ A, int lda,
    const bf16* __restrict__ B, int ldb,
    int kBeg, int kEnd, int m0, int n0, f32x4 acc[4][4])
{
    __shared__ __align__(16) bf16 Als[2][BM][BK];
    __shared__ __align__(16) bf16 Bls[2][BN][BK];
    const int t    = threadIdx.x;
    const int lane = t & 63;
    const int wid  = t >> 6;
    const int wm   = (wid >> 1) * 64;
    const int wn   = (wid & 1) * 64;
    const int fr   = lane & 15;
    const int kq   = lane >> 4;
    const int r_   = t >> 3;
    const int cbs  = (t & 7) ^ (r_ & 7);
    const int dcol = (t & 7) * 8;
    const int cs0  = ((kq)     ^ (fr & 7)) * 8;
    const int cs1  = ((kq + 4) ^ (fr & 7)) * 8;

    const bf16* Ab = A + (size_t)(m0 + r_) * lda + cbs * 8;
    const bf16* Bb = B + (size_t)(n0 + r_) * ldb + cbs * 8;

#define STAGE_G(bufi, kk) do {                                              \
        _Pragma("unroll")                                                   \
        for (int i = 0; i < 4; ++i)                                         \
            gload16(Ab + (kk) + (size_t)(i * 32) * lda,                     \
                    &Als[bufi][i * 32 + r_][dcol]);                         \
        _Pragma("unroll")                                                   \
        for (int i = 0; i < 4; ++i)                                         \
            gload16(Bb + (kk) + (size_t)(i * 32) * ldb,                     \
                    &Bls[bufi][i * 32 + r_][dcol]);                         \
    } while (0)

    int cur = 0;
    STAGE_G(0, kBeg);
    __syncthreads();
    for (int k0 = kBeg; k0 < kEnd; k0 += BK) {
        if (k0 + BK < kEnd) STAGE_G(cur ^ 1, k0 + BK);
        #pragma unroll
        for (int h = 0; h < 2; ++h) {
            const int cs = h ? cs1 : cs0;
            bf16x8 af[4], bg[4];
            #pragma unroll
            for (int f = 0; f < 4; ++f) {
                af[f] = *(const bf16x8*)&Als[cur][wm + f * 16 + fr][cs];
                bg[f] = *(const bf16x8*)&Bls[cur][wn + f * 16 + fr][cs];
            }
            #pragma unroll
            for (int fm = 0; fm < 4; ++fm)
                #pragma unroll
                for (int fn = 0; fn < 4; ++fn)
                    acc[fm][fn] = __builtin_amdgcn_mfma_f32_16x16x32_bf16(
                        af[fm], bg[fn], acc[fm][fn], 0, 0, 0);
        }
        __syncthreads();
        cur ^= 1;
    }
#undef STAGE_G
}

// ---------------------------------------------------------------------------
// 64x128 MFMA GEMM core (4 waves, 2m x 2n of 32x64), double-buffered, 48KB.
// 3 blocks/CU — the session's best-performing core (~690 TF effective).
// ---------------------------------------------------------------------------
__device__ __forceinline__ void gemm_core64(
    const bf16* __restrict__ A, int lda,
    const bf16* __restrict__ B, int ldb,
    int kBeg, int kEnd, int m0, int n0, f32x4 acc[2][4])
{
    __shared__ __align__(16) bf16 Als[2][64][BK];
    __shared__ __align__(16) bf16 Bls[2][BN][BK];
    const int t    = threadIdx.x;
    const int lane = t & 63;
    const int wid  = t >> 6;
    const int wm   = (wid >> 1) * 32;
    const int wn   = (wid & 1) * 64;
    const int fr   = lane & 15;
    const int kq   = lane >> 4;
    const int r_   = t >> 3;
    const int cbs  = (t & 7) ^ (r_ & 7);
    const int dcol = (t & 7) * 8;
    const int cs0  = ((kq)     ^ (fr & 7)) * 8;
    const int cs1  = ((kq + 4) ^ (fr & 7)) * 8;

    const bf16* Ab = A + (size_t)(m0 + r_) * lda + cbs * 8;
    const bf16* Bb = B + (size_t)(n0 + r_) * ldb + cbs * 8;

#define STAGE_G64(bufi, kk) do {                                            \
        _Pragma("unroll")                                                   \
        for (int i = 0; i < 2; ++i)                                         \
            gload16(Ab + (kk) + (size_t)(i * 32) * lda,                     \
                    &Als[bufi][i * 32 + r_][dcol]);                         \
        _Pragma("unroll")                                                   \
        for (int i = 0; i < 4; ++i)                                         \
            gload16(Bb + (kk) + (size_t)(i * 32) * ldb,                     \
                    &Bls[bufi][i * 32 + r_][dcol]);                         \
    } while (0)

    int cur = 0;
    STAGE_G64(0, kBeg);
    __syncthreads();
    for (int k0 = kBeg; k0 < kEnd; k0 += BK) {
        if (k0 + BK < kEnd) STAGE_G64(cur ^ 1, k0 + BK);
        #pragma unroll
        for (int h = 0; h < 2; ++h) {
            const int cs = h ? cs1 : cs0;
            bf16x8 af[2], bg[4];
            #pragma unroll
            for (int f = 0; f < 2; ++f)
                af[f] = *(const bf16x8*)&Als[cur][wm + f * 16 + fr][cs];
            #pragma unroll
            for (int f = 0; f < 4; ++f)
                bg[f] = *(const bf16x8*)&Bls[cur][wn + f * 16 + fr][cs];
            #pragma unroll
            for (int fm = 0; fm < 2; ++fm)
                #pragma unroll
                for (int fn = 0; fn < 4; ++fn)
                    acc[fm][fn] = __builtin_amdgcn_mfma_f32_16x16x32_bf16(
                        af[fm], bg[fn], acc[fm][fn], 0, 0, 0);
        }
        __syncthreads();
        cur ^= 1;
    }
#undef STAGE_G64
}

// ---------------------------------------------------------------------------
// Prep kernels
// ---------------------------------------------------------------------------
__global__ __launch_bounds__(256) void convert_w_kernel(
    const float* __restrict__ qw, const float* __restrict__ kw,
    const float* __restrict__ pw, bf16* __restrict__ dst)
{
    const int which = blockIdx.y;
    const float* src = which == 0 ? qw : which == 1 ? kw : pw;
    const int slot  = which == 2 ? 3 : which;
    bf16* d = dst + (size_t)slot * (CC * CC);
    const int f4 = blockIdx.x * 256 + threadIdx.x;
    float4 v = ((const float4*)src)[f4];
    bf16x4 o;
    o[0] = (bf16)v.x; o[1] = (bf16)v.y; o[2] = (bf16)v.z; o[3] = (bf16)v.w;
    ((bf16x4*)d)[f4] = o;
}

// vwT[k][c] = vw[c][k]
__global__ __launch_bounds__(256) void vwT_kernel(
    const float* __restrict__ vw, bf16* __restrict__ vwT)
{
    const int k0 = blockIdx.x * 64;
    const int c0 = blockIdx.y * 64;
    const int t  = threadIdx.x;
    const int tk = t & 15, tc = t >> 4;
    float o[4][4];
    #pragma unroll
    for (int j = 0; j < 4; ++j) {
        const int c = c0 + tc * 4 + j;
        float4 v = *(const float4*)(vw + (size_t)c * CC + k0 + tk * 4);
        o[j][0] = v.x; o[j][1] = v.y; o[j][2] = v.z; o[j][3] = v.w;
    }
    #pragma unroll
    for (int i = 0; i < 4; ++i) {
        bf16x4 w4;
        w4[0] = (bf16)o[0][i]; w4[1] = (bf16)o[1][i];
        w4[2] = (bf16)o[2][i]; w4[3] = (bf16)o[3][i];
        *(bf16x4*)(vwT + (size_t)(k0 + tk * 4 + i) * CC + c0 + tc * 4) = w4;
    }
}

// wb[o] = sum_c pw[o][c] * vb[c]
__global__ __launch_bounds__(256) void wb_kernel(
    const float* __restrict__ pw, const float* __restrict__ vb,
    float* __restrict__ wb)
{
    const int o = blockIdx.x * 256 + threadIdx.x;
    const float4* row = (const float4*)(pw + (size_t)o * CC);
    const float4* v4  = (const float4*)vb;
    float s = 0.f;
    #pragma unroll 4
    for (int i = 0; i < 128; ++i) {
        float4 a = row[i], b = v4[i];
        s += a.x * b.x + a.y * b.y + a.z * b.z + a.w * b.w;
    }
    wb[o] = s;
}

__global__ __launch_bounds__(256) void gn_stats_kernel(
    const float* __restrict__ x, float* __restrict__ mr)
{
    const int bg = blockIdx.x;
    const float4* base = (const float4*)(x + (size_t)bg * 16 * NN);
    const int t = threadIdx.x;
    float s = 0.f, sq = 0.f;
    #pragma unroll 4
    for (int i = 0; i < 64; ++i) {
        float4 v = base[i * 256 + t];
        s  += v.x + v.y + v.z + v.w;
        sq += v.x * v.x + v.y * v.y + v.z * v.z + v.w * v.w;
    }
    #pragma unroll
    for (int o = 32; o > 0; o >>= 1) { s += __shfl_xor(s, o); sq += __shfl_xor(sq, o); }
    __shared__ float rs[4], rq[4];
    const int lane = t & 63, wid = t >> 6;
    if (lane == 0) { rs[wid] = s; rq[wid] = sq; }
    __syncthreads();
    if (t == 0) {
        float S = rs[0] + rs[1] + rs[2] + rs[3];
        float Q = rq[0] + rq[1] + rq[2] + rq[3];
        const float invn = 1.f / 65536.f;
        float mean = S * invn;
        float var  = Q * invn - mean * mean;
        mr[bg * 2]     = mean;
        mr[bg * 2 + 1] = rsqrtf(var + 1e-6f);
    }
}

// GN apply + transpose: x[b,c,n] fp32 -> hT[b,n,c] bf16
__global__ __launch_bounds__(256) void gn_apply_T_kernel(
    const float* __restrict__ x, const float* __restrict__ gw,
    const float* __restrict__ gb, const float* __restrict__ mr,
    bf16* __restrict__ hT)
{
    const int b  = blockIdx.z;
    const int n0 = blockIdx.x * 64;
    const int c0 = blockIdx.y * 64;
    const int t  = threadIdx.x;
    const int tn = t & 15, tc = t >> 4;
    float o[4][4];
    #pragma unroll
    for (int j = 0; j < 4; ++j) {
        const int c = c0 + tc * 4 + j;
        const int bg = b * 32 + (c >> 4);
        const float mean = mr[bg * 2], rstd = mr[bg * 2 + 1];
        const float w  = gw[c] * rstd;
        const float bb = gb[c] - mean * w;
        float4 v = *(const float4*)(x + ((size_t)(b * CC + c)) * NN + n0 + tn * 4);
        o[j][0] = v.x * w + bb; o[j][1] = v.y * w + bb;
        o[j][2] = v.z * w + bb; o[j][3] = v.w * w + bb;
    }
    bf16* dst = hT + (size_t)b * (size_t)NN * CC;
    #pragma unroll
    for (int i = 0; i < 4; ++i) {
        bf16x4 w4;
        w4[0] = (bf16)o[0][i]; w4[1] = (bf16)o[1][i];
        w4[2] = (bf16)o[2][i]; w4[3] = (bf16)o[3][i];
        *(bf16x4*)(dst + (size_t)(n0 + tn * 4 + i) * CC + c0 + tc * 4) = w4;
    }
}

// ---------------------------------------------------------------------------
// GEMM kernels
// ---------------------------------------------------------------------------
// fw[o][k] = sum_c pw[o][c] * vwT[k][c]  (tiny; 128 core)
__global__ __launch_bounds__(256) void fw_gemm_kernel(
    const bf16* __restrict__ pwb, const bf16* __restrict__ vwT,
    bf16* __restrict__ fw)
{
    const int m0 = blockIdx.y * BM, n0 = blockIdx.x * BN;
    f32x4 acc[4][4] = {};
    gemm_core(pwb, CC, vwT, CC, 0, CC, m0, n0, acc);
    const int lane = threadIdx.x & 63, wid = threadIdx.x >> 6;
    const int wm = (wid >> 1) * 64, wn = (wid & 1) * 64;
    const int cf = lane & 15, rb = (lane >> 4) * 4;
    #pragma unroll
    for (int fm = 0; fm < 4; ++fm)
      #pragma unroll
      for (int fn = 0; fn < 4; ++fn)
        #pragma unroll
        for (int r = 0; r < 4; ++r)
            fw[(size_t)(m0 + wm + fm * 16 + rb + r) * CC
               + (n0 + wn + fn * 16 + cf)] = (bf16)acc[fm][fn][r];
}

// qT/kT[b][i][o] = sum_c hT[b][i][c] * w[o][c] (+bias) (*SCALE_L2E for q)
__global__ __launch_bounds__(256) void qk_gemm_kernel(
    const bf16* __restrict__ hT, const bf16* __restrict__ wbf,
    const float* __restrict__ qb, const float* __restrict__ kb,
    bf16* __restrict__ qT, bf16* __restrict__ kT)
{
    const int z = blockIdx.z, b = z >> 1, w = z & 1;
    const size_t CN = (size_t)CC * NN;
    const bf16* A = hT + (size_t)b * CN;
    const bf16* B = wbf + (size_t)w * CC * CC;
    const float* bias = w ? kb : qb;
    bf16* outp = (w ? kT : qT) + (size_t)b * CN;
    const int m0 = blockIdx.y * 64, n0 = blockIdx.x * 128;
    f32x4 acc[2][4] = {};
    gemm_core64(A, CC, B, CC, 0, CC, m0, n0, acc);
    const int lane = threadIdx.x & 63, wid = threadIdx.x >> 6;
    const int wm = (wid >> 1) * 32, wn = (wid & 1) * 64;
    const int cf = lane & 15, rb = (lane >> 4) * 4;
    #pragma unroll
    for (int fm = 0; fm < 2; ++fm)
      #pragma unroll
      for (int g = 0; g < 4; ++g)
        #pragma unroll
        for (int r = 0; r < 4; ++r) {
            int row = m0 + wm + fm * 16 + rb + r;    // i
            int col = n0 + wn + g * 16 + cf;         // o
            float val = acc[fm][g][r] + bias[col];
            if (w == 0) val *= SCALE_L2E;
            outp[(size_t)row * CC + col] = (bf16)val;
        }
}

// W~[b][o][j] = sum_k fw[o][k] * hT[b][j][k]
__global__ __launch_bounds__(256) void w_gemm_kernel(
    const bf16* __restrict__ fw, const bf16* __restrict__ hT,
    bf16* __restrict__ Wt)
{
    const int b = blockIdx.z;
    const size_t CN = (size_t)CC * NN;
    const int m0 = blockIdx.y * 64, n0 = blockIdx.x * BN;
    f32x4 acc[2][4] = {};
    gemm_core64(fw, CC, hT + (size_t)b * CN, CC, 0, CC, m0, n0, acc);
    bf16* outp = Wt + (size_t)b * CN;
    const int lane = threadIdx.x & 63, wid = threadIdx.x >> 6;
    const int wm = (wid >> 1) * 32, wn = (wid & 1) * 64;
    const int cf = lane & 15, rb = (lane >> 4) * 4;
    #pragma unroll
    for (int fm = 0; fm < 2; ++fm)
      #pragma unroll
      for (int g = 0; g < 4; ++g)
        #pragma unroll
        for (int r = 0; r < 4; ++r)
            outp[(size_t)(m0 + wm + fm * 16 + rb + r) * NN
                 + (n0 + wn + g * 16 + cf)] = (bf16)acc[fm][g][r];
}

// E[b][i][j] = exp2(qT[i,:].kT[j,:]); rowsum[b][i] += partials (atomic)
__global__ __launch_bounds__(256) void se_gemm_kernel(
    const bf16* __restrict__ qT, const bf16* __restrict__ kT,
    bf16* __restrict__ E, float* __restrict__ rowsum)
{
    const int b = blockIdx.z;
    const size_t CN = (size_t)CC * NN;
    const bf16* qT_b = qT + (size_t)b * CN;
    const bf16* kT_b = kT + (size_t)b * CN;
    bf16* E_b = E + (size_t)b * NN * NN;
    float* rs_b = rowsum + (size_t)b * NN;
    const int m0 = blockIdx.y * 64, n0 = blockIdx.x * 128;
    f32x4 acc[2][4] = {};
    gemm_core64(qT_b, CC, kT_b, CC, 0, CC, m0, n0, acc);
    const int lane = threadIdx.x & 63, wid = threadIdx.x >> 6;
    const int wm = (wid >> 1) * 32, wn = (wid & 1) * 64;
    const int cf = lane & 15, rb = (lane >> 4) * 4;
    #pragma unroll
    for (int fm = 0; fm < 2; ++fm)
      #pragma unroll
      for (int g = 0; g < 4; ++g)
        #pragma unroll
        for (int r = 0; r < 4; ++r) {
            float e = exp2f(fminf(acc[fm][g][r], 86.f));
            acc[fm][g][r] = e;
            E_b[(size_t)(m0 + wm + fm * 16 + rb + r) * NN
                + (n0 + wn + g * 16 + cf)] = (bf16)e;
        }
    #pragma unroll
    for (int fm = 0; fm < 2; ++fm)
      #pragma unroll
      for (int r = 0; r < 4; ++r) {
          float s = acc[fm][0][r] + acc[fm][1][r] + acc[fm][2][r] + acc[fm][3][r];
          s += __shfl_xor(s, 1); s += __shfl_xor(s, 2);
          s += __shfl_xor(s, 4); s += __shfl_xor(s, 8);
          if (cf == 0)
              atomicAdd(&rs_b[m0 + wm + fm * 16 + rb + r], s);
      }
}

// out[b][o][n] = (sum_j W~[b][o][j]*E[b][n][j]) / rowsum[b][n]
//               + wb[o] + pb[o] + x[b][o][n]
__global__ __launch_bounds__(256) void pvproj_kernel(
    const bf16* __restrict__ Wt, const bf16* __restrict__ E,
    const float* __restrict__ rowsum, const float* __restrict__ wb,
    const float* __restrict__ pb, const float* __restrict__ x,
    float* __restrict__ outp)
{
    const int b = blockIdx.z;
    const size_t CN = (size_t)CC * NN;
    const int m0 = blockIdx.y * 64, n0 = blockIdx.x * BN;
    f32x4 acc[2][4] = {};
    gemm_core64(Wt + (size_t)b * CN, NN,
                E + (size_t)b * NN * NN, NN, 0, NN, m0, n0, acc);
    const float* rs_b = rowsum + (size_t)b * NN;
    const int lane = threadIdx.x & 63, wid = threadIdx.x >> 6;
    const int wm = (wid >> 1) * 32, wn = (wid & 1) * 64;
    const int cf = lane & 15, rb = (lane >> 4) * 4;
    #pragma unroll
    for (int fm = 0; fm < 2; ++fm)
      #pragma unroll
      for (int g = 0; g < 4; ++g) {
          const int col = n0 + wn + g * 16 + cf;      // n
          const float inv = 1.f / rs_b[col];
          #pragma unroll
          for (int r = 0; r < 4; ++r) {
              const int row = m0 + wm + fm * 16 + rb + r;   // o
              const size_t idx = (size_t)b * CN + (size_t)row * NN + col;
              outp[idx] = acc[fm][g][r] * inv + wb[row] + pb[row] + x[idx];
          }
      }
}

// ---------------------------------------------------------------------------
extern "C" void kernel_launch(void* const* d_in, const int* in_sizes, int n_in,
                              void* d_out, int out_size, void* d_ws, size_t ws_size,
                              hipStream_t stream)
{
    const float* x   = (const float*)d_in[0];
    const float* gnw = (const float*)d_in[1];
    const float* gnb = (const float*)d_in[2];
    const float* qw  = (const float*)d_in[3];
    const float* qb  = (const float*)d_in[4];
    const float* kw  = (const float*)d_in[5];
    const float* kb  = (const float*)d_in[6];
    const float* vw  = (const float*)d_in[7];
    const float* vb  = (const float*)d_in[8];
    const float* pw  = (const float*)d_in[9];
    const float* pb  = (const float*)d_in[10];
    float* outp = (float*)d_out;

    char* ws = (char*)d_ws;
    size_t off = 0;
    auto alloc = [&](size_t bytes) -> char* {
        char* p = ws + off;
        off = (off + bytes + 255) & ~(size_t)255;
        return p;
    };
    const size_t CN = (size_t)CC * NN;
    bf16*  wbf  = (bf16*)alloc(4 * (size_t)CC * CC * sizeof(bf16));   // q,k,vwT,pw
    bf16*  hT   = (bf16*)alloc(2 * CN * sizeof(bf16));                // 8MB
    bf16*  qT   = (bf16*)alloc(2 * CN * sizeof(bf16));                // 8MB
    bf16*  kT   = (bf16*)alloc(2 * CN * sizeof(bf16));                // 8MB
    bf16*  fw   = (bf16*)alloc((size_t)CC * CC * sizeof(bf16));       // 0.5MB
    bf16*  Wt   = (bf16*)alloc(2 * CN * sizeof(bf16));                // 8MB
    bf16*  E    = (bf16*)alloc(2 * (size_t)NN * NN * sizeof(bf16));   // 64MB
    float* rowsum = (float*)alloc(2 * NN * sizeof(float));            // 32KB
    float* wb   = (float*)alloc(CC * sizeof(float));
    float* mr   = (float*)alloc(64 * 2 * sizeof(float));

    bf16* vwT = wbf + 2 * (size_t)CC * CC;
    bf16* pwb = wbf + 3 * (size_t)CC * CC;

    convert_w_kernel<<<dim3(256, 3), 256, 0, stream>>>(qw, kw, pw, wbf);
    vwT_kernel<<<dim3(8, 8), 256, 0, stream>>>(vw, vwT);
    wb_kernel<<<2, 256, 0, stream>>>(pw, vb, wb);
    gn_stats_kernel<<<64, 256, 0, stream>>>(x, mr);
    gn_apply_T_kernel<<<dim3(NN / 64, CC / 64, 2), 256, 0, stream>>>(
        x, gnw, gnb, mr, hT);
    hipMemsetAsync(rowsum, 0, 2 * NN * sizeof(float), stream);

    fw_gemm_kernel<<<dim3(4, 4), 256, 0, stream>>>(pwb, vwT, fw);
    qk_gemm_kernel<<<dim3(CC / 128, NN / 64, 4), 256, 0, stream>>>(
        hT, wbf, qb, kb, qT, kT);
    w_gemm_kernel<<<dim3(NN / 128, CC / 64, 2), 256, 0, stream>>>(fw, hT, Wt);

    se_gemm_kernel<<<dim3(NN / 128, NN / 64, 2), 256, 0, stream>>>(
        qT, kT, E, rowsum);

    pvproj_kernel<<<dim3(NN / 128, CC / 64, 2), 256, 0, stream>>>(
        Wt, E, rowsum, wb, pb, x, outp);
}

// Round 9
// 213.039 us; speedup vs baseline: 1.1520x; 1.0456x over previous
//
#include <hip/hip_runtime.h>

// AttnBlock on MI355X — round 9: R5 (best, 206.7us) + qk/w merged dispatch,
// 256-block gn_stats, XCD-bijective swizzle on se/pvproj. Cores untouched.

typedef __bf16 bf16;
typedef __attribute__((ext_vector_type(8))) __bf16 bf16x8;
typedef __attribute__((ext_vector_type(4))) __bf16 bf16x4;
typedef __attribute__((ext_vector_type(4))) float f32x4;

#define CC 512
#define NN 4096
#define BM 128
#define BN 128
#define BK 64
// 512^-0.5 * log2(e): folded into qT so se uses exp2f directly
#define SCALE_L2E 0.06376237870903338f

__device__ __forceinline__ void gload16(const bf16* g, bf16* l) {
    __builtin_amdgcn_global_load_lds(
        (const __attribute__((address_space(1))) unsigned int*)g,
        (__attribute__((address_space(3))) unsigned int*)l, 16, 0, 0);
}

// ---------------------------------------------------------------------------
// 128x128 MFMA GEMM core (4 waves), 2-phase double-buffered. (R5-proven)
// ---------------------------------------------------------------------------
__device__ __forceinline__ void gemm_core(
    const bf16* __restrict__ A, int lda,
    const bf16* __restrict__ B, int ldb,
    int kBeg, int kEnd, int m0, int n0, f32x4 acc[4][4])
{
    __shared__ __align__(16) bf16 Als[2][BM][BK];
    __shared__ __align__(16) bf16 Bls[2][BN][BK];
    const int t    = threadIdx.x;
    const int lane = t & 63;
    const int wid  = t >> 6;
    const int wm   = (wid >> 1) * 64;
    const int wn   = (wid & 1) * 64;
    const int fr   = lane & 15;
    const int kq   = lane >> 4;
    const int r_   = t >> 3;
    const int cbs  = (t & 7) ^ (r_ & 7);
    const int dcol = (t & 7) * 8;
    const int cs0  = ((kq)     ^ (fr & 7)) * 8;
    const int cs1  = ((kq + 4) ^ (fr & 7)) * 8;

    const bf16* Ab = A + (size_t)(m0 + r_) * lda + cbs * 8;
    const bf16* Bb = B + (size_t)(n0 + r_) * ldb + cbs * 8;

#define STAGE_G(bufi, kk) do {                                              \
        _Pragma("unroll")                                                   \
        for (int i = 0; i < 4; ++i)                                         \
            gload16(Ab + (kk) + (size_t)(i * 32) * lda,                     \
                    &Als[bufi][i * 32 + r_][dcol]);                         \
        _Pragma("unroll")                                                   \
        for (int i = 0; i < 4; ++i)                                         \
            gload16(Bb + (kk) + (size_t)(i * 32) * ldb,                     \
                    &Bls[bufi][i * 32 + r_][dcol]);                         \
    } while (0)

    int cur = 0;
    STAGE_G(0, kBeg);
    __syncthreads();
    for (int k0 = kBeg; k0 < kEnd; k0 += BK) {
        if (k0 + BK < kEnd) STAGE_G(cur ^ 1, k0 + BK);
        #pragma unroll
        for (int h = 0; h < 2; ++h) {
            const int cs = h ? cs1 : cs0;
            bf16x8 af[4], bg[4];
            #pragma unroll
            for (int f = 0; f < 4; ++f) {
                af[f] = *(const bf16x8*)&Als[cur][wm + f * 16 + fr][cs];
                bg[f] = *(const bf16x8*)&Bls[cur][wn + f * 16 + fr][cs];
            }
            #pragma unroll
            for (int fm = 0; fm < 4; ++fm)
                #pragma unroll
                for (int fn = 0; fn < 4; ++fn)
                    acc[fm][fn] = __builtin_amdgcn_mfma_f32_16x16x32_bf16(
                        af[fm], bg[fn], acc[fm][fn], 0, 0, 0);
        }
        __syncthreads();
        cur ^= 1;
    }
#undef STAGE_G
}

// ---------------------------------------------------------------------------
// 64x128 MFMA GEMM core (4 waves), double-buffered, 48KB. (R5 pvproj core)
// ---------------------------------------------------------------------------
__device__ __forceinline__ void gemm_core64(
    const bf16* __restrict__ A, int lda,
    const bf16* __restrict__ B, int ldb,
    int kBeg, int kEnd, int m0, int n0, f32x4 acc[2][4])
{
    __shared__ __align__(16) bf16 Als[2][64][BK];
    __shared__ __align__(16) bf16 Bls[2][BN][BK];
    const int t    = threadIdx.x;
    const int lane = t & 63;
    const int wid  = t >> 6;
    const int wm   = (wid >> 1) * 32;
    const int wn   = (wid & 1) * 64;
    const int fr   = lane & 15;
    const int kq   = lane >> 4;
    const int r_   = t >> 3;
    const int cbs  = (t & 7) ^ (r_ & 7);
    const int dcol = (t & 7) * 8;
    const int cs0  = ((kq)     ^ (fr & 7)) * 8;
    const int cs1  = ((kq + 4) ^ (fr & 7)) * 8;

    const bf16* Ab = A + (size_t)(m0 + r_) * lda + cbs * 8;
    const bf16* Bb = B + (size_t)(n0 + r_) * ldb + cbs * 8;

#define STAGE_G64(bufi, kk) do {                                            \
        _Pragma("unroll")                                                   \
        for (int i = 0; i < 2; ++i)                                         \
            gload16(Ab + (kk) + (size_t)(i * 32) * lda,                     \
                    &Als[bufi][i * 32 + r_][dcol]);                         \
        _Pragma("unroll")                                                   \
        for (int i = 0; i < 4; ++i)                                         \
            gload16(Bb + (kk) + (size_t)(i * 32) * ldb,                     \
                    &Bls[bufi][i * 32 + r_][dcol]);                         \
    } while (0)

    int cur = 0;
    STAGE_G64(0, kBeg);
    __syncthreads();
    for (int k0 = kBeg; k0 < kEnd; k0 += BK) {
        if (k0 + BK < kEnd) STAGE_G64(cur ^ 1, k0 + BK);
        #pragma unroll
        for (int h = 0; h < 2; ++h) {
            const int cs = h ? cs1 : cs0;
            bf16x8 af[2], bg[4];
            #pragma unroll
            for (int f = 0; f < 2; ++f)
                af[f] = *(const bf16x8*)&Als[cur][wm + f * 16 + fr][cs];
            #pragma unroll
            for (int f = 0; f < 4; ++f)
                bg[f] = *(const bf16x8*)&Bls[cur][wn + f * 16 + fr][cs];
            #pragma unroll
            for (int fm = 0; fm < 2; ++fm)
                #pragma unroll
                for (int fn = 0; fn < 4; ++fn)
                    acc[fm][fn] = __builtin_amdgcn_mfma_f32_16x16x32_bf16(
                        af[fm], bg[fn], acc[fm][fn], 0, 0, 0);
        }
        __syncthreads();
        cur ^= 1;
    }
#undef STAGE_G64
}

// ---------------------------------------------------------------------------
// Prep kernels
// ---------------------------------------------------------------------------
__global__ __launch_bounds__(256) void convert_w_kernel(
    const float* __restrict__ qw, const float* __restrict__ kw,
    const float* __restrict__ pw, bf16* __restrict__ dst)
{
    const int which = blockIdx.y;
    const float* src = which == 0 ? qw : which == 1 ? kw : pw;
    const int slot  = which == 2 ? 3 : which;
    bf16* d = dst + (size_t)slot * (CC * CC);
    const int f4 = blockIdx.x * 256 + threadIdx.x;
    float4 v = ((const float4*)src)[f4];
    bf16x4 o;
    o[0] = (bf16)v.x; o[1] = (bf16)v.y; o[2] = (bf16)v.z; o[3] = (bf16)v.w;
    ((bf16x4*)d)[f4] = o;
}

// vwT[k][c] = vw[c][k]
__global__ __launch_bounds__(256) void vwT_kernel(
    const float* __restrict__ vw, bf16* __restrict__ vwT)
{
    const int k0 = blockIdx.x * 64;
    const int c0 = blockIdx.y * 64;
    const int t  = threadIdx.x;
    const int tk = t & 15, tc = t >> 4;
    float o[4][4];
    #pragma unroll
    for (int j = 0; j < 4; ++j) {
        const int c = c0 + tc * 4 + j;
        float4 v = *(const float4*)(vw + (size_t)c * CC + k0 + tk * 4);
        o[j][0] = v.x; o[j][1] = v.y; o[j][2] = v.z; o[j][3] = v.w;
    }
    #pragma unroll
    for (int i = 0; i < 4; ++i) {
        bf16x4 w4;
        w4[0] = (bf16)o[0][i]; w4[1] = (bf16)o[1][i];
        w4[2] = (bf16)o[2][i]; w4[3] = (bf16)o[3][i];
        *(bf16x4*)(vwT + (size_t)(k0 + tk * 4 + i) * CC + c0 + tc * 4) = w4;
    }
}

// wb[o] = sum_c pw[o][c] * vb[c]
__global__ __launch_bounds__(256) void wb_kernel(
    const float* __restrict__ pw, const float* __restrict__ vb,
    float* __restrict__ wb)
{
    const int o = blockIdx.x * 256 + threadIdx.x;
    const float4* row = (const float4*)(pw + (size_t)o * CC);
    const float4* v4  = (const float4*)vb;
    float s = 0.f;
    #pragma unroll 4
    for (int i = 0; i < 128; ++i) {
        float4 a = row[i], b = v4[i];
        s += a.x * b.x + a.y * b.y + a.z * b.z + a.w * b.w;
    }
    wb[o] = s;
}

// 256 blocks: 4 sub-blocks per (b,g); atomics of raw {sum, sumsq} into mr.
__global__ __launch_bounds__(256) void gn_stats_kernel(
    const float* __restrict__ x, float* __restrict__ mr)
{
    const int bg = blockIdx.x >> 2;                  // 0..63
    const int qq = blockIdx.x & 3;                   // quarter
    const float4* base = (const float4*)(x + (size_t)bg * 16 * NN);
    const int t = threadIdx.x;
    float s = 0.f, sq = 0.f;
    #pragma unroll 4
    for (int i = 0; i < 16; ++i) {
        float4 v = base[(qq * 16 + i) * 256 + t];
        s  += v.x + v.y + v.z + v.w;
        sq += v.x * v.x + v.y * v.y + v.z * v.z + v.w * v.w;
    }
    #pragma unroll
    for (int o = 32; o > 0; o >>= 1) { s += __shfl_xor(s, o); sq += __shfl_xor(sq, o); }
    __shared__ float rs[4], rq[4];
    const int lane = t & 63, wid = t >> 6;
    if (lane == 0) { rs[wid] = s; rq[wid] = sq; }
    __syncthreads();
    if (t == 0) {
        atomicAdd(&mr[bg * 2],     rs[0] + rs[1] + rs[2] + rs[3]);
        atomicAdd(&mr[bg * 2 + 1], rq[0] + rq[1] + rq[2] + rq[3]);
    }
}

// GN apply + transpose: x[b,c,n] fp32 -> hT[b,n,c] bf16 (mr holds raw sums)
__global__ __launch_bounds__(256) void gn_apply_T_kernel(
    const float* __restrict__ x, const float* __restrict__ gw,
    const float* __restrict__ gb, const float* __restrict__ mr,
    bf16* __restrict__ hT)
{
    const int b  = blockIdx.z;
    const int n0 = blockIdx.x * 64;
    const int c0 = blockIdx.y * 64;
    const int t  = threadIdx.x;
    const int tn = t & 15, tc = t >> 4;
    float o[4][4];
    #pragma unroll
    for (int j = 0; j < 4; ++j) {
        const int c = c0 + tc * 4 + j;
        const int bg = b * 32 + (c >> 4);
        const float invn = 1.f / 65536.f;
        const float mean = mr[bg * 2] * invn;
        const float var  = mr[bg * 2 + 1] * invn - mean * mean;
        const float rstd = rsqrtf(var + 1e-6f);
        const float w  = gw[c] * rstd;
        const float bb = gb[c] - mean * w;
        float4 v = *(const float4*)(x + ((size_t)(b * CC + c)) * NN + n0 + tn * 4);
        o[j][0] = v.x * w + bb; o[j][1] = v.y * w + bb;
        o[j][2] = v.z * w + bb; o[j][3] = v.w * w + bb;
    }
    bf16* dst = hT + (size_t)b * (size_t)NN * CC;
    #pragma unroll
    for (int i = 0; i < 4; ++i) {
        bf16x4 w4;
        w4[0] = (bf16)o[0][i]; w4[1] = (bf16)o[1][i];
        w4[2] = (bf16)o[2][i]; w4[3] = (bf16)o[3][i];
        *(bf16x4*)(dst + (size_t)(n0 + tn * 4 + i) * CC + c0 + tc * 4) = w4;
    }
}

// ---------------------------------------------------------------------------
// GEMM kernels
// ---------------------------------------------------------------------------
// fw[o][k] = sum_c pw[o][c] * vwT[k][c]
__global__ __launch_bounds__(256) void fw_gemm_kernel(
    const bf16* __restrict__ pwb, const bf16* __restrict__ vwT,
    bf16* __restrict__ fw)
{
    const int m0 = blockIdx.y * BM, n0 = blockIdx.x * BN;
    f32x4 acc[4][4] = {};
    gemm_core(pwb, CC, vwT, CC, 0, CC, m0, n0, acc);
    const int lane = threadIdx.x & 63, wid = threadIdx.x >> 6;
    const int wm = (wid >> 1) * 64, wn = (wid & 1) * 64;
    const int cf = lane & 15, rb = (lane >> 4) * 4;
    #pragma unroll
    for (int fm = 0; fm < 4; ++fm)
      #pragma unroll
      for (int fn = 0; fn < 4; ++fn)
        #pragma unroll
        for (int r = 0; r < 4; ++r)
            fw[(size_t)(m0 + wm + fm * 16 + rb + r) * CC
               + (n0 + wn + fn * 16 + cf)] = (bf16)acc[fm][fn][r];
}

// Merged q/k/w GEMMs: 768 blocks, XCD-chunked swizzle.
// seg 0..3: q/k  (w=seg&1, b=seg>>1): out[i][o] = hT.wqk + bias (q*=SCALE)
// seg 4..5: W~   (b=seg-4):           Wt[o][j]  = fw.hT
__global__ __launch_bounds__(256) void qkw_gemm_kernel(
    const bf16* __restrict__ hT, const bf16* __restrict__ wbf,
    const bf16* __restrict__ fw,
    const float* __restrict__ qb, const float* __restrict__ kb,
    bf16* __restrict__ qT, bf16* __restrict__ kT, bf16* __restrict__ Wt)
{
    const size_t CN = (size_t)CC * NN;
    int id = blockIdx.x;
    id = (id & 7) * 96 + (id >> 3);          // bijective: 768 = 8*96
    const int seg = id >> 7, s = id & 127;

    const bf16* A; const bf16* B;
    int m0, n0, ldo; bf16* outp; const float* bias; int role;
    if (seg < 4) {
        role = seg & 1;                      // 0=q, 1=k
        const int b = seg >> 1;
        A = hT + (size_t)b * CN;
        B = wbf + (size_t)role * CC * CC;
        m0 = (s >> 2) * 128; n0 = (s & 3) * 128;
        outp = (role ? kT : qT) + (size_t)b * CN; ldo = CC;
        bias = role ? kb : qb;
    } else {
        role = 2;
        const int b = seg - 4;
        A = fw;
        B = hT + (size_t)b * CN;
        m0 = (s >> 5) * 128; n0 = (s & 31) * 128;
        outp = Wt + (size_t)b * CN; ldo = NN;
        bias = nullptr;
    }
    f32x4 acc[4][4] = {};
    gemm_core(A, CC, B, CC, 0, CC, m0, n0, acc);
    const int lane = threadIdx.x & 63, wid = threadIdx.x >> 6;
    const int wm = (wid >> 1) * 64, wn = (wid & 1) * 64;
    const int cf = lane & 15, rb = (lane >> 4) * 4;
    #pragma unroll
    for (int fm = 0; fm < 4; ++fm)
      #pragma unroll
      for (int fn = 0; fn < 4; ++fn) {
          const int col = n0 + wn + fn * 16 + cf;
          const float bv = (role < 2) ? bias[col] : 0.f;
          #pragma unroll
          for (int r = 0; r < 4; ++r) {
              const int row = m0 + wm + fm * 16 + rb + r;
              float val = acc[fm][fn][r] + bv;
              if (role == 0) val *= SCALE_L2E;
              outp[(size_t)row * ldo + col] = (bf16)val;
          }
      }
}

// E[b][i][j] = exp2(qT[i,:].kT[j,:]); rowsum[b][i] += partials (atomic)
// Flat grid 2048 with per-batch XCD-chunked swizzle (1024 = 8*128).
__global__ __launch_bounds__(256) void se_gemm_kernel(
    const bf16* __restrict__ qT, const bf16* __restrict__ kT,
    bf16* __restrict__ E, float* __restrict__ rowsum)
{
    int id = blockIdx.x;
    int b = 0;
    if (id >= 1024) { b = 1; id -= 1024; }
    id = (id & 7) * 128 + (id >> 3);         // bijective: 1024 = 8*128
    const int m0 = (id >> 5) * 128, n0 = (id & 31) * 128;

    const size_t CN = (size_t)CC * NN;
    const bf16* qT_b = qT + (size_t)b * CN;
    const bf16* kT_b = kT + (size_t)b * CN;
    bf16* E_b = E + (size_t)b * NN * NN;
    float* rs_b = rowsum + (size_t)b * NN;
    f32x4 acc[4][4] = {};
    gemm_core(qT_b, CC, kT_b, CC, 0, CC, m0, n0, acc);
    const int lane = threadIdx.x & 63, wid = threadIdx.x >> 6;
    const int wm = (wid >> 1) * 64, wn = (wid & 1) * 64;
    const int cf = lane & 15, rb = (lane >> 4) * 4;
    #pragma unroll
    for (int fm = 0; fm < 4; ++fm)
      #pragma unroll
      for (int fn = 0; fn < 4; ++fn)
        #pragma unroll
        for (int r = 0; r < 4; ++r) {
            float e = exp2f(fminf(acc[fm][fn][r], 86.f));
            acc[fm][fn][r] = e;
            E_b[(size_t)(m0 + wm + fm * 16 + rb + r) * NN
                + (n0 + wn + fn * 16 + cf)] = (bf16)e;
        }
    #pragma unroll
    for (int fm = 0; fm < 4; ++fm)
      #pragma unroll
      for (int r = 0; r < 4; ++r) {
          float s = acc[fm][0][r] + acc[fm][1][r] + acc[fm][2][r] + acc[fm][3][r];
          s += __shfl_xor(s, 1); s += __shfl_xor(s, 2);
          s += __shfl_xor(s, 4); s += __shfl_xor(s, 8);
          if (cf == 0)
              atomicAdd(&rs_b[m0 + wm + fm * 16 + rb + r], s);
      }
}

// out[b][o][n] = (sum_j W~[b][o][j]*E[b][n][j]) / rowsum[b][n]
//               + wb[o] + pb[o] + x[b][o][n]
// Flat grid 512 with per-batch XCD-chunked swizzle (256 = 8*32).
__global__ __launch_bounds__(256) void pvproj_kernel(
    const bf16* __restrict__ Wt, const bf16* __restrict__ E,
    const float* __restrict__ rowsum, const float* __restrict__ wb,
    const float* __restrict__ pb, const float* __restrict__ x,
    float* __restrict__ outp)
{
    int id = blockIdx.x;
    int b = 0;
    if (id >= 256) { b = 1; id -= 256; }
    id = (id & 7) * 32 + (id >> 3);          // bijective: 256 = 8*32
    const int m0 = (id & 7) * 64;            // o-tile (varies fastest in chunk)
    const int n0 = (id >> 3) * 128;          // n-tile

    const size_t CN = (size_t)CC * NN;
    f32x4 acc[2][4] = {};
    gemm_core64(Wt + (size_t)b * CN, NN,
                E + (size_t)b * NN * NN, NN, 0, NN, m0, n0, acc);
    const float* rs_b = rowsum + (size_t)b * NN;
    const int lane = threadIdx.x & 63, wid = threadIdx.x >> 6;
    const int wm = (wid >> 1) * 32, wn = (wid & 1) * 64;
    const int cf = lane & 15, rb = (lane >> 4) * 4;
    #pragma unroll
    for (int fm = 0; fm < 2; ++fm)
      #pragma unroll
      for (int g = 0; g < 4; ++g) {
          const int col = n0 + wn + g * 16 + cf;      // n
          const float inv = 1.f / rs_b[col];
          #pragma unroll
          for (int r = 0; r < 4; ++r) {
              const int row = m0 + wm + fm * 16 + rb + r;   // o
              const size_t idx = (size_t)b * CN + (size_t)row * NN + col;
              outp[idx] = acc[fm][g][r] * inv + wb[row] + pb[row] + x[idx];
          }
      }
}

// ---------------------------------------------------------------------------
extern "C" void kernel_launch(void* const* d_in, const int* in_sizes, int n_in,
                              void* d_out, int out_size, void* d_ws, size_t ws_size,
                              hipStream_t stream)
{
    const float* x   = (const float*)d_in[0];
    const float* gnw = (const float*)d_in[1];
    const float* gnb = (const float*)d_in[2];
    const float* qw  = (const float*)d_in[3];
    const float* qb  = (const float*)d_in[4];
    const float* kw  = (const float*)d_in[5];
    const float* kb  = (const float*)d_in[6];
    const float* vw  = (const float*)d_in[7];
    const float* vb  = (const float*)d_in[8];
    const float* pw  = (const float*)d_in[9];
    const float* pb  = (const float*)d_in[10];
    float* outp = (float*)d_out;

    char* ws = (char*)d_ws;
    size_t off = 0;
    auto alloc = [&](size_t bytes) -> char* {
        char* p = ws + off;
        off = (off + bytes + 255) & ~(size_t)255;
        return p;
    };
    const size_t CN = (size_t)CC * NN;
    bf16*  wbf  = (bf16*)alloc(4 * (size_t)CC * CC * sizeof(bf16));   // q,k,vwT,pw
    bf16*  hT   = (bf16*)alloc(2 * CN * sizeof(bf16));                // 8MB
    bf16*  qT   = (bf16*)alloc(2 * CN * sizeof(bf16));                // 8MB
    bf16*  kT   = (bf16*)alloc(2 * CN * sizeof(bf16));                // 8MB
    bf16*  fw   = (bf16*)alloc((size_t)CC * CC * sizeof(bf16));       // 0.5MB
    bf16*  Wt   = (bf16*)alloc(2 * CN * sizeof(bf16));                // 8MB
    bf16*  E    = (bf16*)alloc(2 * (size_t)NN * NN * sizeof(bf16));   // 64MB
    float* rowsum = (float*)alloc(2 * NN * sizeof(float));            // 32KB
    float* wb   = (float*)alloc(CC * sizeof(float));
    float* mr   = (float*)alloc(64 * 2 * sizeof(float));

    bf16* vwT = wbf + 2 * (size_t)CC * CC;
    bf16* pwb = wbf + 3 * (size_t)CC * CC;

    convert_w_kernel<<<dim3(256, 3), 256, 0, stream>>>(qw, kw, pw, wbf);
    vwT_kernel<<<dim3(8, 8), 256, 0, stream>>>(vw, vwT);
    wb_kernel<<<2, 256, 0, stream>>>(pw, vb, wb);
    hipMemsetAsync(mr, 0, 64 * 2 * sizeof(float), stream);
    gn_stats_kernel<<<256, 256, 0, stream>>>(x, mr);
    gn_apply_T_kernel<<<dim3(NN / 64, CC / 64, 2), 256, 0, stream>>>(
        x, gnw, gnb, mr, hT);
    hipMemsetAsync(rowsum, 0, 2 * NN * sizeof(float), stream);

    fw_gemm_kernel<<<dim3(4, 4), 256, 0, stream>>>(pwb, vwT, fw);
    qkw_gemm_kernel<<<768, 256, 0, stream>>>(
        hT, wbf, fw, qb, kb, qT, kT, Wt);

    se_gemm_kernel<<<2048, 256, 0, stream>>>(qT, kT, E, rowsum);

    pvproj_kernel<<<512, 256, 0, stream>>>(
        Wt, E, rowsum, wb, pb, x, outp);
}

// Round 10
// 205.987 us; speedup vs baseline: 1.1915x; 1.0342x over previous
//
#include <hip/hip_runtime.h>

// AttnBlock on MI355X — round 10: R5 verbatim (best, 206.7us) + merged qkw
// dispatch (linear mapping) + 256-block gn_stats. No XCD swizzles (R9 showed
// they thrash per-XCD L2 here: se FETCH 40->70MB, 74->82us).

typedef __bf16 bf16;
typedef __attribute__((ext_vector_type(8))) __bf16 bf16x8;
typedef __attribute__((ext_vector_type(4))) __bf16 bf16x4;
typedef __attribute__((ext_vector_type(4))) float f32x4;

#define CC 512
#define NN 4096
#define BM 128
#define BN 128
#define BK 64
// 512^-0.5 * log2(e): folded into qT so se uses exp2f directly
#define SCALE_L2E 0.06376237870903338f

__device__ __forceinline__ void gload16(const bf16* g, bf16* l) {
    __builtin_amdgcn_global_load_lds(
        (const __attribute__((address_space(1))) unsigned int*)g,
        (__attribute__((address_space(3))) unsigned int*)l, 16, 0, 0);
}

// ---------------------------------------------------------------------------
// 128x128 MFMA GEMM core (4 waves), 2-phase double-buffered. (R5-proven)
// ---------------------------------------------------------------------------
__device__ __forceinline__ void gemm_core(
    const bf16* __restrict__ A, int lda,
    const bf16* __restrict__ B, int ldb,
    int kBeg, int kEnd, int m0, int n0, f32x4 acc[4][4])
{
    __shared__ __align__(16) bf16 Als[2][BM][BK];
    __shared__ __align__(16) bf16 Bls[2][BN][BK];
    const int t    = threadIdx.x;
    const int lane = t & 63;
    const int wid  = t >> 6;
    const int wm   = (wid >> 1) * 64;
    const int wn   = (wid & 1) * 64;
    const int fr   = lane & 15;
    const int kq   = lane >> 4;
    const int r_   = t >> 3;
    const int cbs  = (t & 7) ^ (r_ & 7);
    const int dcol = (t & 7) * 8;
    const int cs0  = ((kq)     ^ (fr & 7)) * 8;
    const int cs1  = ((kq + 4) ^ (fr & 7)) * 8;

    const bf16* Ab = A + (size_t)(m0 + r_) * lda + cbs * 8;
    const bf16* Bb = B + (size_t)(n0 + r_) * ldb + cbs * 8;

#define STAGE_G(bufi, kk) do {                                              \
        _Pragma("unroll")                                                   \
        for (int i = 0; i < 4; ++i)                                         \
            gload16(Ab + (kk) + (size_t)(i * 32) * lda,                     \
                    &Als[bufi][i * 32 + r_][dcol]);                         \
        _Pragma("unroll")                                                   \
        for (int i = 0; i < 4; ++i)                                         \
            gload16(Bb + (kk) + (size_t)(i * 32) * ldb,                     \
                    &Bls[bufi][i * 32 + r_][dcol]);                         \
    } while (0)

    int cur = 0;
    STAGE_G(0, kBeg);
    __syncthreads();
    for (int k0 = kBeg; k0 < kEnd; k0 += BK) {
        if (k0 + BK < kEnd) STAGE_G(cur ^ 1, k0 + BK);
        #pragma unroll
        for (int h = 0; h < 2; ++h) {
            const int cs = h ? cs1 : cs0;
            bf16x8 af[4], bg[4];
            #pragma unroll
            for (int f = 0; f < 4; ++f) {
                af[f] = *(const bf16x8*)&Als[cur][wm + f * 16 + fr][cs];
                bg[f] = *(const bf16x8*)&Bls[cur][wn + f * 16 + fr][cs];
            }
            #pragma unroll
            for (int fm = 0; fm < 4; ++fm)
                #pragma unroll
                for (int fn = 0; fn < 4; ++fn)
                    acc[fm][fn] = __builtin_amdgcn_mfma_f32_16x16x32_bf16(
                        af[fm], bg[fn], acc[fm][fn], 0, 0, 0);
        }
        __syncthreads();
        cur ^= 1;
    }
#undef STAGE_G
}

// ---------------------------------------------------------------------------
// 64x128 MFMA GEMM core (4 waves), double-buffered, 48KB. (R5 pvproj core)
// ---------------------------------------------------------------------------
__device__ __forceinline__ void gemm_core64(
    const bf16* __restrict__ A, int lda,
    const bf16* __restrict__ B, int ldb,
    int kBeg, int kEnd, int m0, int n0, f32x4 acc[2][4])
{
    __shared__ __align__(16) bf16 Als[2][64][BK];
    __shared__ __align__(16) bf16 Bls[2][BN][BK];
    const int t    = threadIdx.x;
    const int lane = t & 63;
    const int wid  = t >> 6;
    const int wm   = (wid >> 1) * 32;
    const int wn   = (wid & 1) * 64;
    const int fr   = lane & 15;
    const int kq   = lane >> 4;
    const int r_   = t >> 3;
    const int cbs  = (t & 7) ^ (r_ & 7);
    const int dcol = (t & 7) * 8;
    const int cs0  = ((kq)     ^ (fr & 7)) * 8;
    const int cs1  = ((kq + 4) ^ (fr & 7)) * 8;

    const bf16* Ab = A + (size_t)(m0 + r_) * lda + cbs * 8;
    const bf16* Bb = B + (size_t)(n0 + r_) * ldb + cbs * 8;

#define STAGE_G64(bufi, kk) do {                                            \
        _Pragma("unroll")                                                   \
        for (int i = 0; i < 2; ++i)                                         \
            gload16(Ab + (kk) + (size_t)(i * 32) * lda,                     \
                    &Als[bufi][i * 32 + r_][dcol]);                         \
        _Pragma("unroll")                                                   \
        for (int i = 0; i < 4; ++i)                                         \
            gload16(Bb + (kk) + (size_t)(i * 32) * ldb,                     \
                    &Bls[bufi][i * 32 + r_][dcol]);                         \
    } while (0)

    int cur = 0;
    STAGE_G64(0, kBeg);
    __syncthreads();
    for (int k0 = kBeg; k0 < kEnd; k0 += BK) {
        if (k0 + BK < kEnd) STAGE_G64(cur ^ 1, k0 + BK);
        #pragma unroll
        for (int h = 0; h < 2; ++h) {
            const int cs = h ? cs1 : cs0;
            bf16x8 af[2], bg[4];
            #pragma unroll
            for (int f = 0; f < 2; ++f)
                af[f] = *(const bf16x8*)&Als[cur][wm + f * 16 + fr][cs];
            #pragma unroll
            for (int f = 0; f < 4; ++f)
                bg[f] = *(const bf16x8*)&Bls[cur][wn + f * 16 + fr][cs];
            #pragma unroll
            for (int fm = 0; fm < 2; ++fm)
                #pragma unroll
                for (int fn = 0; fn < 4; ++fn)
                    acc[fm][fn] = __builtin_amdgcn_mfma_f32_16x16x32_bf16(
                        af[fm], bg[fn], acc[fm][fn], 0, 0, 0);
        }
        __syncthreads();
        cur ^= 1;
    }
#undef STAGE_G64
}

// ---------------------------------------------------------------------------
// Prep kernels
// ---------------------------------------------------------------------------
__global__ __launch_bounds__(256) void convert_w_kernel(
    const float* __restrict__ qw, const float* __restrict__ kw,
    const float* __restrict__ pw, bf16* __restrict__ dst)
{
    const int which = blockIdx.y;
    const float* src = which == 0 ? qw : which == 1 ? kw : pw;
    const int slot  = which == 2 ? 3 : which;
    bf16* d = dst + (size_t)slot * (CC * CC);
    const int f4 = blockIdx.x * 256 + threadIdx.x;
    float4 v = ((const float4*)src)[f4];
    bf16x4 o;
    o[0] = (bf16)v.x; o[1] = (bf16)v.y; o[2] = (bf16)v.z; o[3] = (bf16)v.w;
    ((bf16x4*)d)[f4] = o;
}

// vwT[k][c] = vw[c][k]
__global__ __launch_bounds__(256) void vwT_kernel(
    const float* __restrict__ vw, bf16* __restrict__ vwT)
{
    const int k0 = blockIdx.x * 64;
    const int c0 = blockIdx.y * 64;
    const int t  = threadIdx.x;
    const int tk = t & 15, tc = t >> 4;
    float o[4][4];
    #pragma unroll
    for (int j = 0; j < 4; ++j) {
        const int c = c0 + tc * 4 + j;
        float4 v = *(const float4*)(vw + (size_t)c * CC + k0 + tk * 4);
        o[j][0] = v.x; o[j][1] = v.y; o[j][2] = v.z; o[j][3] = v.w;
    }
    #pragma unroll
    for (int i = 0; i < 4; ++i) {
        bf16x4 w4;
        w4[0] = (bf16)o[0][i]; w4[1] = (bf16)o[1][i];
        w4[2] = (bf16)o[2][i]; w4[3] = (bf16)o[3][i];
        *(bf16x4*)(vwT + (size_t)(k0 + tk * 4 + i) * CC + c0 + tc * 4) = w4;
    }
}

// wb[o] = sum_c pw[o][c] * vb[c]
__global__ __launch_bounds__(256) void wb_kernel(
    const float* __restrict__ pw, const float* __restrict__ vb,
    float* __restrict__ wb)
{
    const int o = blockIdx.x * 256 + threadIdx.x;
    const float4* row = (const float4*)(pw + (size_t)o * CC);
    const float4* v4  = (const float4*)vb;
    float s = 0.f;
    #pragma unroll 4
    for (int i = 0; i < 128; ++i) {
        float4 a = row[i], b = v4[i];
        s += a.x * b.x + a.y * b.y + a.z * b.z + a.w * b.w;
    }
    wb[o] = s;
}

// 256 blocks: 4 sub-blocks per (b,g); atomics of raw {sum, sumsq} into mr.
__global__ __launch_bounds__(256) void gn_stats_kernel(
    const float* __restrict__ x, float* __restrict__ mr)
{
    const int bg = blockIdx.x >> 2;                  // 0..63
    const int qq = blockIdx.x & 3;                   // quarter
    const float4* base = (const float4*)(x + (size_t)bg * 16 * NN);
    const int t = threadIdx.x;
    float s = 0.f, sq = 0.f;
    #pragma unroll 4
    for (int i = 0; i < 16; ++i) {
        float4 v = base[(qq * 16 + i) * 256 + t];
        s  += v.x + v.y + v.z + v.w;
        sq += v.x * v.x + v.y * v.y + v.z * v.z + v.w * v.w;
    }
    #pragma unroll
    for (int o = 32; o > 0; o >>= 1) { s += __shfl_xor(s, o); sq += __shfl_xor(sq, o); }
    __shared__ float rs[4], rq[4];
    const int lane = t & 63, wid = t >> 6;
    if (lane == 0) { rs[wid] = s; rq[wid] = sq; }
    __syncthreads();
    if (t == 0) {
        atomicAdd(&mr[bg * 2],     rs[0] + rs[1] + rs[2] + rs[3]);
        atomicAdd(&mr[bg * 2 + 1], rq[0] + rq[1] + rq[2] + rq[3]);
    }
}

// GN apply + transpose: x[b,c,n] fp32 -> hT[b,n,c] bf16 (mr holds raw sums)
__global__ __launch_bounds__(256) void gn_apply_T_kernel(
    const float* __restrict__ x, const float* __restrict__ gw,
    const float* __restrict__ gb, const float* __restrict__ mr,
    bf16* __restrict__ hT)
{
    const int b  = blockIdx.z;
    const int n0 = blockIdx.x * 64;
    const int c0 = blockIdx.y * 64;
    const int t  = threadIdx.x;
    const int tn = t & 15, tc = t >> 4;
    float o[4][4];
    #pragma unroll
    for (int j = 0; j < 4; ++j) {
        const int c = c0 + tc * 4 + j;
        const int bg = b * 32 + (c >> 4);
        const float invn = 1.f / 65536.f;
        const float mean = mr[bg * 2] * invn;
        const float var  = mr[bg * 2 + 1] * invn - mean * mean;
        const float rstd = rsqrtf(var + 1e-6f);
        const float w  = gw[c] * rstd;
        const float bb = gb[c] - mean * w;
        float4 v = *(const float4*)(x + ((size_t)(b * CC + c)) * NN + n0 + tn * 4);
        o[j][0] = v.x * w + bb; o[j][1] = v.y * w + bb;
        o[j][2] = v.z * w + bb; o[j][3] = v.w * w + bb;
    }
    bf16* dst = hT + (size_t)b * (size_t)NN * CC;
    #pragma unroll
    for (int i = 0; i < 4; ++i) {
        bf16x4 w4;
        w4[0] = (bf16)o[0][i]; w4[1] = (bf16)o[1][i];
        w4[2] = (bf16)o[2][i]; w4[3] = (bf16)o[3][i];
        *(bf16x4*)(dst + (size_t)(n0 + tn * 4 + i) * CC + c0 + tc * 4) = w4;
    }
}

// ---------------------------------------------------------------------------
// GEMM kernels
// ---------------------------------------------------------------------------
// fw[o][k] = sum_c pw[o][c] * vwT[k][c]
__global__ __launch_bounds__(256) void fw_gemm_kernel(
    const bf16* __restrict__ pwb, const bf16* __restrict__ vwT,
    bf16* __restrict__ fw)
{
    const int m0 = blockIdx.y * BM, n0 = blockIdx.x * BN;
    f32x4 acc[4][4] = {};
    gemm_core(pwb, CC, vwT, CC, 0, CC, m0, n0, acc);
    const int lane = threadIdx.x & 63, wid = threadIdx.x >> 6;
    const int wm = (wid >> 1) * 64, wn = (wid & 1) * 64;
    const int cf = lane & 15, rb = (lane >> 4) * 4;
    #pragma unroll
    for (int fm = 0; fm < 4; ++fm)
      #pragma unroll
      for (int fn = 0; fn < 4; ++fn)
        #pragma unroll
        for (int r = 0; r < 4; ++r)
            fw[(size_t)(m0 + wm + fm * 16 + rb + r) * CC
               + (n0 + wn + fn * 16 + cf)] = (bf16)acc[fm][fn][r];
}

// Merged q/k/w GEMMs: 768 blocks, LINEAR mapping (no swizzle).
// seg 0..3: q/k (role=seg&1, b=seg>>1): out[i][o] = hT.wqk + bias (q*=SCALE)
// seg 4..5: W~  (b=seg-4):              Wt[o][j]  = fw.hT
__global__ __launch_bounds__(256) void qkw_gemm_kernel(
    const bf16* __restrict__ hT, const bf16* __restrict__ wbf,
    const bf16* __restrict__ fw,
    const float* __restrict__ qb, const float* __restrict__ kb,
    bf16* __restrict__ qT, bf16* __restrict__ kT, bf16* __restrict__ Wt)
{
    const size_t CN = (size_t)CC * NN;
    const int id = blockIdx.x;
    const int seg = id >> 7, s = id & 127;

    const bf16* A; const bf16* B;
    int m0, n0, ldo; bf16* outp; const float* bias; int role;
    if (seg < 4) {
        role = seg & 1;                      // 0=q, 1=k
        const int b = seg >> 1;
        A = hT + (size_t)b * CN;
        B = wbf + (size_t)role * CC * CC;
        m0 = (s >> 2) * 128; n0 = (s & 3) * 128;
        outp = (role ? kT : qT) + (size_t)b * CN; ldo = CC;
        bias = role ? kb : qb;
    } else {
        role = 2;
        const int b = seg - 4;
        A = fw;
        B = hT + (size_t)b * CN;
        m0 = (s >> 5) * 128; n0 = (s & 31) * 128;
        outp = Wt + (size_t)b * CN; ldo = NN;
        bias = nullptr;
    }
    f32x4 acc[4][4] = {};
    gemm_core(A, CC, B, CC, 0, CC, m0, n0, acc);
    const int lane = threadIdx.x & 63, wid = threadIdx.x >> 6;
    const int wm = (wid >> 1) * 64, wn = (wid & 1) * 64;
    const int cf = lane & 15, rb = (lane >> 4) * 4;
    #pragma unroll
    for (int fm = 0; fm < 4; ++fm)
      #pragma unroll
      for (int fn = 0; fn < 4; ++fn) {
          const int col = n0 + wn + fn * 16 + cf;
          const float bv = (role < 2) ? bias[col] : 0.f;
          #pragma unroll
          for (int r = 0; r < 4; ++r) {
              const int row = m0 + wm + fm * 16 + rb + r;
              float val = acc[fm][fn][r] + bv;
              if (role == 0) val *= SCALE_L2E;
              outp[(size_t)row * ldo + col] = (bf16)val;
          }
      }
}

// E[b][i][j] = exp2(qT.kT); rowsum[b][i] += partials (atomic). (R5 verbatim)
__global__ __launch_bounds__(256) void se_gemm_kernel(
    const bf16* __restrict__ qT, const bf16* __restrict__ kT,
    bf16* __restrict__ E, float* __restrict__ rowsum)
{
    const int b = blockIdx.z;
    const size_t CN = (size_t)CC * NN;
    const bf16* qT_b = qT + (size_t)b * CN;
    const bf16* kT_b = kT + (size_t)b * CN;
    bf16* E_b = E + (size_t)b * NN * NN;
    float* rs_b = rowsum + (size_t)b * NN;
    const int m0 = blockIdx.y * BM, n0 = blockIdx.x * BN;
    f32x4 acc[4][4] = {};
    gemm_core(qT_b, CC, kT_b, CC, 0, CC, m0, n0, acc);
    const int lane = threadIdx.x & 63, wid = threadIdx.x >> 6;
    const int wm = (wid >> 1) * 64, wn = (wid & 1) * 64;
    const int cf = lane & 15, rb = (lane >> 4) * 4;
    #pragma unroll
    for (int fm = 0; fm < 4; ++fm)
      #pragma unroll
      for (int fn = 0; fn < 4; ++fn)
        #pragma unroll
        for (int r = 0; r < 4; ++r) {
            float e = exp2f(fminf(acc[fm][fn][r], 86.f));
            acc[fm][fn][r] = e;
            E_b[(size_t)(m0 + wm + fm * 16 + rb + r) * NN
                + (n0 + wn + fn * 16 + cf)] = (bf16)e;
        }
    #pragma unroll
    for (int fm = 0; fm < 4; ++fm)
      #pragma unroll
      for (int r = 0; r < 4; ++r) {
          float s = acc[fm][0][r] + acc[fm][1][r] + acc[fm][2][r] + acc[fm][3][r];
          s += __shfl_xor(s, 1); s += __shfl_xor(s, 2);
          s += __shfl_xor(s, 4); s += __shfl_xor(s, 8);
          if (cf == 0)
              atomicAdd(&rs_b[m0 + wm + fm * 16 + rb + r], s);
      }
}

// out[b][o][n] = (sum_j W~[b][o][j]*E[b][n][j]) / rowsum[b][n]
//               + wb[o] + pb[o] + x[b][o][n]          (R5 verbatim)
__global__ __launch_bounds__(256) void pvproj_kernel(
    const bf16* __restrict__ Wt, const bf16* __restrict__ E,
    const float* __restrict__ rowsum, const float* __restrict__ wb,
    const float* __restrict__ pb, const float* __restrict__ x,
    float* __restrict__ outp)
{
    const int b = blockIdx.z;
    const size_t CN = (size_t)CC * NN;
    const int m0 = blockIdx.y * 64, n0 = blockIdx.x * BN;
    f32x4 acc[2][4] = {};
    gemm_core64(Wt + (size_t)b * CN, NN, E + (size_t)b * NN * NN, NN,
                0, NN, m0, n0, acc);
    const float* rs_b = rowsum + (size_t)b * NN;
    const int lane = threadIdx.x & 63, wid = threadIdx.x >> 6;
    const int wm = (wid >> 1) * 32, wn = (wid & 1) * 64;
    const int cf = lane & 15, rb = (lane >> 4) * 4;
    #pragma unroll
    for (int fm = 0; fm < 2; ++fm)
      #pragma unroll
      for (int g = 0; g < 4; ++g) {
          const int col = n0 + wn + g * 16 + cf;      // n
          const float inv = 1.f / rs_b[col];
          #pragma unroll
          for (int r = 0; r < 4; ++r) {
              const int row = m0 + wm + fm * 16 + rb + r;   // o
              const size_t idx = (size_t)b * CN + (size_t)row * NN + col;
              outp[idx] = acc[fm][g][r] * inv + wb[row] + pb[row] + x[idx];
          }
      }
}

// ---------------------------------------------------------------------------
extern "C" void kernel_launch(void* const* d_in, const int* in_sizes, int n_in,
                              void* d_out, int out_size, void* d_ws, size_t ws_size,
                              hipStream_t stream)
{
    const float* x   = (const float*)d_in[0];
    const float* gnw = (const float*)d_in[1];
    const float* gnb = (const float*)d_in[2];
    const float* qw  = (const float*)d_in[3];
    const float* qb  = (const float*)d_in[4];
    const float* kw  = (const float*)d_in[5];
    const float* kb  = (const float*)d_in[6];
    const float* vw  = (const float*)d_in[7];
    const float* vb  = (const float*)d_in[8];
    const float* pw  = (const float*)d_in[9];
    const float* pb  = (const float*)d_in[10];
    float* outp = (float*)d_out;

    char* ws = (char*)d_ws;
    size_t off = 0;
    auto alloc = [&](size_t bytes) -> char* {
        char* p = ws + off;
        off = (off + bytes + 255) & ~(size_t)255;
        return p;
    };
    const size_t CN = (size_t)CC * NN;
    bf16*  wbf  = (bf16*)alloc(4 * (size_t)CC * CC * sizeof(bf16));   // q,k,vwT,pw
    bf16*  hT   = (bf16*)alloc(2 * CN * sizeof(bf16));                // 8MB
    bf16*  qT   = (bf16*)alloc(2 * CN * sizeof(bf16));                // 8MB
    bf16*  kT   = (bf16*)alloc(2 * CN * sizeof(bf16));                // 8MB
    bf16*  fw   = (bf16*)alloc((size_t)CC * CC * sizeof(bf16));       // 0.5MB
    bf16*  Wt   = (bf16*)alloc(2 * CN * sizeof(bf16));                // 8MB
    bf16*  E    = (bf16*)alloc(2 * (size_t)NN * NN * sizeof(bf16));   // 64MB
    float* rowsum = (float*)alloc(2 * NN * sizeof(float));            // 32KB
    float* wb   = (float*)alloc(CC * sizeof(float));
    float* mr   = (float*)alloc(64 * 2 * sizeof(float));

    bf16* vwT = wbf + 2 * (size_t)CC * CC;
    bf16* pwb = wbf + 3 * (size_t)CC * CC;

    convert_w_kernel<<<dim3(256, 3), 256, 0, stream>>>(qw, kw, pw, wbf);
    vwT_kernel<<<dim3(8, 8), 256, 0, stream>>>(vw, vwT);
    wb_kernel<<<2, 256, 0, stream>>>(pw, vb, wb);
    hipMemsetAsync(mr, 0, 64 * 2 * sizeof(float), stream);
    gn_stats_kernel<<<256, 256, 0, stream>>>(x, mr);
    gn_apply_T_kernel<<<dim3(NN / 64, CC / 64, 2), 256, 0, stream>>>(
        x, gnw, gnb, mr, hT);
    hipMemsetAsync(rowsum, 0, 2 * NN * sizeof(float), stream);

    fw_gemm_kernel<<<dim3(4, 4), 256, 0, stream>>>(pwb, vwT, fw);
    qkw_gemm_kernel<<<768, 256, 0, stream>>>(
        hT, wbf, fw, qb, kb, qT, kT, Wt);

    se_gemm_kernel<<<dim3(NN / BN, NN / BM, 2), 256, 0, stream>>>(
        qT, kT, E, rowsum);

    pvproj_kernel<<<dim3(NN / BN, 8, 2), 256, 0, stream>>>(
        Wt, E, rowsum, wb, pb, x, outp);
}

// Round 11
// 202.044 us; speedup vs baseline: 1.2147x; 1.0195x over previous
//
#include <hip/hip_runtime.h>
#include <type_traits>

// AttnBlock on MI355X — round 11: R10 + faithful m201-style 8-phase 256x256
// kernel for se (fine ds_read/stage/MFMA interleave, vmcnt(6) @ phases 4/8,
// setprio around MFMA). Everything else identical to R10 (best, 206.0us).

typedef __bf16 bf16;
typedef __attribute__((ext_vector_type(8))) __bf16 bf16x8;
typedef __attribute__((ext_vector_type(4))) __bf16 bf16x4;
typedef __attribute__((ext_vector_type(4))) float f32x4;

#define CC 512
#define NN 4096
#define BM 128
#define BN 128
#define BK 64
// 512^-0.5 * log2(e): folded into qT so se uses exp2f directly
#define SCALE_L2E 0.06376237870903338f

__device__ __forceinline__ void gload16(const bf16* g, bf16* l) {
    __builtin_amdgcn_global_load_lds(
        (const __attribute__((address_space(1))) unsigned int*)g,
        (__attribute__((address_space(3))) unsigned int*)l, 16, 0, 0);
}

// ---------------------------------------------------------------------------
// 128x128 MFMA GEMM core (4 waves), 2-phase double-buffered. (R5-proven)
// ---------------------------------------------------------------------------
__device__ __forceinline__ void gemm_core(
    const bf16* __restrict__ A, int lda,
    const bf16* __restrict__ B, int ldb,
    int kBeg, int kEnd, int m0, int n0, f32x4 acc[4][4])
{
    __shared__ __align__(16) bf16 Als[2][BM][BK];
    __shared__ __align__(16) bf16 Bls[2][BN][BK];
    const int t    = threadIdx.x;
    const int lane = t & 63;
    const int wid  = t >> 6;
    const int wm   = (wid >> 1) * 64;
    const int wn   = (wid & 1) * 64;
    const int fr   = lane & 15;
    const int kq   = lane >> 4;
    const int r_   = t >> 3;
    const int cbs  = (t & 7) ^ (r_ & 7);
    const int dcol = (t & 7) * 8;
    const int cs0  = ((kq)     ^ (fr & 7)) * 8;
    const int cs1  = ((kq + 4) ^ (fr & 7)) * 8;

    const bf16* Ab = A + (size_t)(m0 + r_) * lda + cbs * 8;
    const bf16* Bb = B + (size_t)(n0 + r_) * ldb + cbs * 8;

#define STAGE_G(bufi, kk) do {                                              \
        _Pragma("unroll")                                                   \
        for (int i = 0; i < 4; ++i)                                         \
            gload16(Ab + (kk) + (size_t)(i * 32) * lda,                     \
                    &Als[bufi][i * 32 + r_][dcol]);                         \
        _Pragma("unroll")                                                   \
        for (int i = 0; i < 4; ++i)                                         \
            gload16(Bb + (kk) + (size_t)(i * 32) * ldb,                     \
                    &Bls[bufi][i * 32 + r_][dcol]);                         \
    } while (0)

    int cur = 0;
    STAGE_G(0, kBeg);
    __syncthreads();
    for (int k0 = kBeg; k0 < kEnd; k0 += BK) {
        if (k0 + BK < kEnd) STAGE_G(cur ^ 1, k0 + BK);
        #pragma unroll
        for (int h = 0; h < 2; ++h) {
            const int cs = h ? cs1 : cs0;
            bf16x8 af[4], bg[4];
            #pragma unroll
            for (int f = 0; f < 4; ++f) {
                af[f] = *(const bf16x8*)&Als[cur][wm + f * 16 + fr][cs];
                bg[f] = *(const bf16x8*)&Bls[cur][wn + f * 16 + fr][cs];
            }
            #pragma unroll
            for (int fm = 0; fm < 4; ++fm)
                #pragma unroll
                for (int fn = 0; fn < 4; ++fn)
                    acc[fm][fn] = __builtin_amdgcn_mfma_f32_16x16x32_bf16(
                        af[fm], bg[fn], acc[fm][fn], 0, 0, 0);
        }
        __syncthreads();
        cur ^= 1;
    }
#undef STAGE_G
}

// ---------------------------------------------------------------------------
// 64x128 MFMA GEMM core (4 waves), double-buffered, 48KB. (R5 pvproj core)
// ---------------------------------------------------------------------------
__device__ __forceinline__ void gemm_core64(
    const bf16* __restrict__ A, int lda,
    const bf16* __restrict__ B, int ldb,
    int kBeg, int kEnd, int m0, int n0, f32x4 acc[2][4])
{
    __shared__ __align__(16) bf16 Als[2][64][BK];
    __shared__ __align__(16) bf16 Bls[2][BN][BK];
    const int t    = threadIdx.x;
    const int lane = t & 63;
    const int wid  = t >> 6;
    const int wm   = (wid >> 1) * 32;
    const int wn   = (wid & 1) * 64;
    const int fr   = lane & 15;
    const int kq   = lane >> 4;
    const int r_   = t >> 3;
    const int cbs  = (t & 7) ^ (r_ & 7);
    const int dcol = (t & 7) * 8;
    const int cs0  = ((kq)     ^ (fr & 7)) * 8;
    const int cs1  = ((kq + 4) ^ (fr & 7)) * 8;

    const bf16* Ab = A + (size_t)(m0 + r_) * lda + cbs * 8;
    const bf16* Bb = B + (size_t)(n0 + r_) * ldb + cbs * 8;

#define STAGE_G64(bufi, kk) do {                                            \
        _Pragma("unroll")                                                   \
        for (int i = 0; i < 2; ++i)                                         \
            gload16(Ab + (kk) + (size_t)(i * 32) * lda,                     \
                    &Als[bufi][i * 32 + r_][dcol]);                         \
        _Pragma("unroll")                                                   \
        for (int i = 0; i < 4; ++i)                                         \
            gload16(Bb + (kk) + (size_t)(i * 32) * ldb,                     \
                    &Bls[bufi][i * 32 + r_][dcol]);                         \
    } while (0)

    int cur = 0;
    STAGE_G64(0, kBeg);
    __syncthreads();
    for (int k0 = kBeg; k0 < kEnd; k0 += BK) {
        if (k0 + BK < kEnd) STAGE_G64(cur ^ 1, k0 + BK);
        #pragma unroll
        for (int h = 0; h < 2; ++h) {
            const int cs = h ? cs1 : cs0;
            bf16x8 af[2], bg[4];
            #pragma unroll
            for (int f = 0; f < 2; ++f)
                af[f] = *(const bf16x8*)&Als[cur][wm + f * 16 + fr][cs];
            #pragma unroll
            for (int f = 0; f < 4; ++f)
                bg[f] = *(const bf16x8*)&Bls[cur][wn + f * 16 + fr][cs];
            #pragma unroll
            for (int fm = 0; fm < 2; ++fm)
                #pragma unroll
                for (int fn = 0; fn < 4; ++fn)
                    acc[fm][fn] = __builtin_amdgcn_mfma_f32_16x16x32_bf16(
                        af[fm], bg[fn], acc[fm][fn], 0, 0, 0);
        }
        __syncthreads();
        cur ^= 1;
    }
#undef STAGE_G64
}

// ---------------------------------------------------------------------------
// Prep kernels
// ---------------------------------------------------------------------------
__global__ __launch_bounds__(256) void convert_w_kernel(
    const float* __restrict__ qw, const float* __restrict__ kw,
    const float* __restrict__ pw, bf16* __restrict__ dst)
{
    const int which = blockIdx.y;
    const float* src = which == 0 ? qw : which == 1 ? kw : pw;
    const int slot  = which == 2 ? 3 : which;
    bf16* d = dst + (size_t)slot * (CC * CC);
    const int f4 = blockIdx.x * 256 + threadIdx.x;
    float4 v = ((const float4*)src)[f4];
    bf16x4 o;
    o[0] = (bf16)v.x; o[1] = (bf16)v.y; o[2] = (bf16)v.z; o[3] = (bf16)v.w;
    ((bf16x4*)d)[f4] = o;
}

// vwT[k][c] = vw[c][k]
__global__ __launch_bounds__(256) void vwT_kernel(
    const float* __restrict__ vw, bf16* __restrict__ vwT)
{
    const int k0 = blockIdx.x * 64;
    const int c0 = blockIdx.y * 64;
    const int t  = threadIdx.x;
    const int tk = t & 15, tc = t >> 4;
    float o[4][4];
    #pragma unroll
    for (int j = 0; j < 4; ++j) {
        const int c = c0 + tc * 4 + j;
        float4 v = *(const float4*)(vw + (size_t)c * CC + k0 + tk * 4);
        o[j][0] = v.x; o[j][1] = v.y; o[j][2] = v.z; o[j][3] = v.w;
    }
    #pragma unroll
    for (int i = 0; i < 4; ++i) {
        bf16x4 w4;
        w4[0] = (bf16)o[0][i]; w4[1] = (bf16)o[1][i];
        w4[2] = (bf16)o[2][i]; w4[3] = (bf16)o[3][i];
        *(bf16x4*)(vwT + (size_t)(k0 + tk * 4 + i) * CC + c0 + tc * 4) = w4;
    }
}

// wb[o] = sum_c pw[o][c] * vb[c]
__global__ __launch_bounds__(256) void wb_kernel(
    const float* __restrict__ pw, const float* __restrict__ vb,
    float* __restrict__ wb)
{
    const int o = blockIdx.x * 256 + threadIdx.x;
    const float4* row = (const float4*)(pw + (size_t)o * CC);
    const float4* v4  = (const float4*)vb;
    float s = 0.f;
    #pragma unroll 4
    for (int i = 0; i < 128; ++i) {
        float4 a = row[i], b = v4[i];
        s += a.x * b.x + a.y * b.y + a.z * b.z + a.w * b.w;
    }
    wb[o] = s;
}

// 256 blocks: 4 sub-blocks per (b,g); atomics of raw {sum, sumsq} into mr.
__global__ __launch_bounds__(256) void gn_stats_kernel(
    const float* __restrict__ x, float* __restrict__ mr)
{
    const int bg = blockIdx.x >> 2;
    const int qq = blockIdx.x & 3;
    const float4* base = (const float4*)(x + (size_t)bg * 16 * NN);
    const int t = threadIdx.x;
    float s = 0.f, sq = 0.f;
    #pragma unroll 4
    for (int i = 0; i < 16; ++i) {
        float4 v = base[(qq * 16 + i) * 256 + t];
        s  += v.x + v.y + v.z + v.w;
        sq += v.x * v.x + v.y * v.y + v.z * v.z + v.w * v.w;
    }
    #pragma unroll
    for (int o = 32; o > 0; o >>= 1) { s += __shfl_xor(s, o); sq += __shfl_xor(sq, o); }
    __shared__ float rs[4], rq[4];
    const int lane = t & 63, wid = t >> 6;
    if (lane == 0) { rs[wid] = s; rq[wid] = sq; }
    __syncthreads();
    if (t == 0) {
        atomicAdd(&mr[bg * 2],     rs[0] + rs[1] + rs[2] + rs[3]);
        atomicAdd(&mr[bg * 2 + 1], rq[0] + rq[1] + rq[2] + rq[3]);
    }
}

// GN apply + transpose: x[b,c,n] fp32 -> hT[b,n,c] bf16 (mr holds raw sums)
__global__ __launch_bounds__(256) void gn_apply_T_kernel(
    const float* __restrict__ x, const float* __restrict__ gw,
    const float* __restrict__ gb, const float* __restrict__ mr,
    bf16* __restrict__ hT)
{
    const int b  = blockIdx.z;
    const int n0 = blockIdx.x * 64;
    const int c0 = blockIdx.y * 64;
    const int t  = threadIdx.x;
    const int tn = t & 15, tc = t >> 4;
    float o[4][4];
    #pragma unroll
    for (int j = 0; j < 4; ++j) {
        const int c = c0 + tc * 4 + j;
        const int bg = b * 32 + (c >> 4);
        const float invn = 1.f / 65536.f;
        const float mean = mr[bg * 2] * invn;
        const float var  = mr[bg * 2 + 1] * invn - mean * mean;
        const float rstd = rsqrtf(var + 1e-6f);
        const float w  = gw[c] * rstd;
        const float bb = gb[c] - mean * w;
        float4 v = *(const float4*)(x + ((size_t)(b * CC + c)) * NN + n0 + tn * 4);
        o[j][0] = v.x * w + bb; o[j][1] = v.y * w + bb;
        o[j][2] = v.z * w + bb; o[j][3] = v.w * w + bb;
    }
    bf16* dst = hT + (size_t)b * (size_t)NN * CC;
    #pragma unroll
    for (int i = 0; i < 4; ++i) {
        bf16x4 w4;
        w4[0] = (bf16)o[0][i]; w4[1] = (bf16)o[1][i];
        w4[2] = (bf16)o[2][i]; w4[3] = (bf16)o[3][i];
        *(bf16x4*)(dst + (size_t)(n0 + tn * 4 + i) * CC + c0 + tc * 4) = w4;
    }
}

// ---------------------------------------------------------------------------
// GEMM kernels
// ---------------------------------------------------------------------------
// fw[o][k] = sum_c pw[o][c] * vwT[k][c]
__global__ __launch_bounds__(256) void fw_gemm_kernel(
    const bf16* __restrict__ pwb, const bf16* __restrict__ vwT,
    bf16* __restrict__ fw)
{
    const int m0 = blockIdx.y * BM, n0 = blockIdx.x * BN;
    f32x4 acc[4][4] = {};
    gemm_core(pwb, CC, vwT, CC, 0, CC, m0, n0, acc);
    const int lane = threadIdx.x & 63, wid = threadIdx.x >> 6;
    const int wm = (wid >> 1) * 64, wn = (wid & 1) * 64;
    const int cf = lane & 15, rb = (lane >> 4) * 4;
    #pragma unroll
    for (int fm = 0; fm < 4; ++fm)
      #pragma unroll
      for (int fn = 0; fn < 4; ++fn)
        #pragma unroll
        for (int r = 0; r < 4; ++r)
            fw[(size_t)(m0 + wm + fm * 16 + rb + r) * CC
               + (n0 + wn + fn * 16 + cf)] = (bf16)acc[fm][fn][r];
}

// Merged q/k/w GEMMs: 768 blocks, linear mapping.
__global__ __launch_bounds__(256) void qkw_gemm_kernel(
    const bf16* __restrict__ hT, const bf16* __restrict__ wbf,
    const bf16* __restrict__ fw,
    const float* __restrict__ qb, const float* __restrict__ kb,
    bf16* __restrict__ qT, bf16* __restrict__ kT, bf16* __restrict__ Wt)
{
    const size_t CN = (size_t)CC * NN;
    const int id = blockIdx.x;
    const int seg = id >> 7, s = id & 127;

    const bf16* A; const bf16* B;
    int m0, n0, ldo; bf16* outp; const float* bias; int role;
    if (seg < 4) {
        role = seg & 1;
        const int b = seg >> 1;
        A = hT + (size_t)b * CN;
        B = wbf + (size_t)role * CC * CC;
        m0 = (s >> 2) * 128; n0 = (s & 3) * 128;
        outp = (role ? kT : qT) + (size_t)b * CN; ldo = CC;
        bias = role ? kb : qb;
    } else {
        role = 2;
        const int b = seg - 4;
        A = fw;
        B = hT + (size_t)b * CN;
        m0 = (s >> 5) * 128; n0 = (s & 31) * 128;
        outp = Wt + (size_t)b * CN; ldo = NN;
        bias = nullptr;
    }
    f32x4 acc[4][4] = {};
    gemm_core(A, CC, B, CC, 0, CC, m0, n0, acc);
    const int lane = threadIdx.x & 63, wid = threadIdx.x >> 6;
    const int wm = (wid >> 1) * 64, wn = (wid & 1) * 64;
    const int cf = lane & 15, rb = (lane >> 4) * 4;
    #pragma unroll
    for (int fm = 0; fm < 4; ++fm)
      #pragma unroll
      for (int fn = 0; fn < 4; ++fn) {
          const int col = n0 + wn + fn * 16 + cf;
          const float bv = (role < 2) ? bias[col] : 0.f;
          #pragma unroll
          for (int r = 0; r < 4; ++r) {
              const int row = m0 + wm + fm * 16 + rb + r;
              float val = acc[fm][fn][r] + bv;
              if (role == 0) val *= SCALE_L2E;
              outp[(size_t)row * ldo + col] = (bf16)val;
          }
      }
}

// ---------------------------------------------------------------------------
// se: 8-phase 256x256 pipelined kernel (m201 template, plain HIP).
// E[b][i][j] = exp2(qT[i,:].kT[j,:]); rowsum[b][i] += partials (atomic).
// 512 thr = 8 waves (2m x 4n), wave tile 128x64, BK=64, K=512 -> 4 iters.
// LDS 128KB = 2 dbuf x (A 256x64 + B 256x64) bf16.
// Per phase: {4(or 12) ds_read_b128 || stage 1 half-tile (2 gload16)} ->
//   barrier -> lgkmcnt(0)+sched_barrier -> setprio(1) 16 MFMA setprio(0)
//   -> barrier.  vmcnt(6) only at phases 4 and 8.
// ---------------------------------------------------------------------------
__global__ __launch_bounds__(512) void se8_kernel(
    const bf16* __restrict__ qT, const bf16* __restrict__ kT,
    bf16* __restrict__ E, float* __restrict__ rowsum)
{
    __shared__ __align__(16) bf16 Als[2][256][64];
    __shared__ __align__(16) bf16 Bls[2][256][64];

    const int b = blockIdx.z;
    const size_t CN = (size_t)CC * NN;
    const bf16* A = qT + (size_t)b * CN;   // [4096][512]
    const bf16* Bm = kT + (size_t)b * CN;
    const int m0 = blockIdx.y * 256, n0 = blockIdx.x * 256;

    const int t    = threadIdx.x;
    const int lane = t & 63;
    const int wid  = t >> 6;
    const int wr   = wid >> 2;             // 0..1
    const int wc   = wid & 3;              // 0..3
    const int fr   = lane & 15;
    const int kq   = lane >> 4;
    const int cs0  = ((kq)     ^ (fr & 7)) * 8;
    const int cs1  = ((kq + 4) ^ (fr & 7)) * 8;

    const int rr0 = t >> 3;                // 0..63
    const int bl0 = t & 7;

    // stage B(kt) half h (rows h*128 .. h*128+127); linear-in-t LDS dest.
    auto SB = [&](int kt, int h) {
        #pragma unroll
        for (int j = 0; j < 2; ++j) {
            const int r = rr0 + j * 64 + h * 128;
            const int src = bl0 ^ (r & 7);
            gload16(Bm + (size_t)(n0 + r) * CC + kt * 64 + src * 8,
                    &Bls[kt & 1][r][bl0 * 8]);
        }
    };
    // stage A(kt) strips: s=0 -> rows 0-63 & 128-191 (quadrants 0,1 of both
    // wave-halves); s=1 -> rows 64-127 & 192-255 (quadrants 2,3).
    auto SA = [&](int kt, int s) {
        #pragma unroll
        for (int j = 0; j < 2; ++j) {
            const int r = rr0 + s * 64 + j * 128;
            const int src = bl0 ^ (r & 7);
            gload16(A + (size_t)(m0 + r) * CC + kt * 64 + src * 8,
                    &Als[kt & 1][r][bl0 * 8]);
        }
    };

    f32x4 acc[8][4] = {};
    bf16x8 bf_[4][2];

    // one phase: quadrant Q (compile-time) of K-tile kt.
    // waitmode: 0 none, 1 vmcnt(6), 2 vmcnt(0)
    auto phase = [&](int kt, auto qc, auto stage, int waitmode) {
        constexpr int Q = decltype(qc)::value;
        const int db = kt & 1;
        if (Q == 0) {
            #pragma unroll
            for (int g = 0; g < 4; ++g) {
                const int br = wc * 64 + g * 16 + fr;
                bf_[g][0] = *(const bf16x8*)&Bls[db][br][cs0];
                bf_[g][1] = *(const bf16x8*)&Bls[db][br][cs1];
            }
        }
        bf16x8 af_[2][2];
        #pragma unroll
        for (int f = 0; f < 2; ++f) {
            const int ar = wr * 128 + Q * 32 + f * 16 + fr;
            af_[f][0] = *(const bf16x8*)&Als[db][ar][cs0];
            af_[f][1] = *(const bf16x8*)&Als[db][ar][cs1];
        }
        stage();
        if (waitmode == 1)      asm volatile("s_waitcnt vmcnt(6)" ::: "memory");
        else if (waitmode == 2) asm volatile("s_waitcnt vmcnt(0)" ::: "memory");
        __builtin_amdgcn_s_barrier();
        asm volatile("s_waitcnt lgkmcnt(0)" ::: "memory");
        __builtin_amdgcn_sched_barrier(0);
        __builtin_amdgcn_s_setprio(1);
        #pragma unroll
        for (int kh = 0; kh < 2; ++kh)
            #pragma unroll
            for (int f = 0; f < 2; ++f)
                #pragma unroll
                for (int g = 0; g < 4; ++g)
                    acc[Q * 2 + f][g] = __builtin_amdgcn_mfma_f32_16x16x32_bf16(
                        af_[f][kh], bf_[g][kh], acc[Q * 2 + f][g], 0, 0, 0);
        __builtin_amdgcn_s_setprio(0);
        __builtin_amdgcn_s_barrier();
    };

    // Prologue: stage tile 0 fully + tile 1 (B both halves, A q01) = 7 halves.
    SB(0, 0); SB(0, 1); SA(0, 0); SA(0, 1);
    SB(1, 0); SB(1, 1); SA(1, 0);
    asm volatile("s_waitcnt vmcnt(6)" ::: "memory");  // tile 0 landed
    __builtin_amdgcn_s_barrier();

    #define IC(v) std::integral_constant<int, v>{}
    for (int i = 0; i < 4; ++i) {
        const int k0t = 2 * i, k1t = 2 * i + 1;
        const int T2 = 2 * i + 2, T3 = 2 * i + 3;
        const bool more = (i < 3);
        const int wm_ = more ? 1 : 2;
        phase(k0t, IC(0), [&]{ SA(k1t, 1); },            0);
        phase(k0t, IC(1), [&]{ if (more) SB(T2, 0); },   0);
        phase(k0t, IC(2), [&]{ if (more) SB(T2, 1); },   0);
        phase(k0t, IC(3), [&]{ if (more) SA(T2, 0); },   wm_);
        phase(k1t, IC(0), [&]{ if (more) SA(T2, 1); },   0);
        phase(k1t, IC(1), [&]{ if (more) SB(T3, 0); },   0);
        phase(k1t, IC(2), [&]{ if (more) SB(T3, 1); },   0);
        phase(k1t, IC(3), [&]{ if (more) SA(T3, 0); },   wm_);
    }
    #undef IC

    // Epilogue: exp2, store E, rowsum atomics.
    bf16* E_b = E + (size_t)b * NN * NN;
    float* rs_b = rowsum + (size_t)b * NN;
    const int cf = fr, rb = kq * 4;
    #pragma unroll
    for (int fm = 0; fm < 8; ++fm)
      #pragma unroll
      for (int g = 0; g < 4; ++g)
        #pragma unroll
        for (int r = 0; r < 4; ++r) {
            float e = exp2f(fminf(acc[fm][g][r], 86.f));
            acc[fm][g][r] = e;
            E_b[(size_t)(m0 + wr * 128 + fm * 16 + rb + r) * NN
                + (n0 + wc * 64 + g * 16 + cf)] = (bf16)e;
        }
    #pragma unroll
    for (int fm = 0; fm < 8; ++fm)
      #pragma unroll
      for (int r = 0; r < 4; ++r) {
          float s = acc[fm][0][r] + acc[fm][1][r] + acc[fm][2][r] + acc[fm][3][r];
          s += __shfl_xor(s, 1); s += __shfl_xor(s, 2);
          s += __shfl_xor(s, 4); s += __shfl_xor(s, 8);
          if (cf == 0)
              atomicAdd(&rs_b[m0 + wr * 128 + fm * 16 + rb + r], s);
      }
}

// out[b][o][n] = (sum_j W~[b][o][j]*E[b][n][j]) / rowsum[b][n]
//               + wb[o] + pb[o] + x[b][o][n]          (R5 verbatim)
__global__ __launch_bounds__(256) void pvproj_kernel(
    const bf16* __restrict__ Wt, const bf16* __restrict__ E,
    const float* __restrict__ rowsum, const float* __restrict__ wb,
    const float* __restrict__ pb, const float* __restrict__ x,
    float* __restrict__ outp)
{
    const int b = blockIdx.z;
    const size_t CN = (size_t)CC * NN;
    const int m0 = blockIdx.y * 64, n0 = blockIdx.x * BN;
    f32x4 acc[2][4] = {};
    gemm_core64(Wt + (size_t)b * CN, NN, E + (size_t)b * NN * NN, NN,
                0, NN, m0, n0, acc);
    const float* rs_b = rowsum + (size_t)b * NN;
    const int lane = threadIdx.x & 63, wid = threadIdx.x >> 6;
    const int wm = (wid >> 1) * 32, wn = (wid & 1) * 64;
    const int cf = lane & 15, rb = (lane >> 4) * 4;
    #pragma unroll
    for (int fm = 0; fm < 2; ++fm)
      #pragma unroll
      for (int g = 0; g < 4; ++g) {
          const int col = n0 + wn + g * 16 + cf;
          const float inv = 1.f / rs_b[col];
          #pragma unroll
          for (int r = 0; r < 4; ++r) {
              const int row = m0 + wm + fm * 16 + rb + r;
              const size_t idx = (size_t)b * CN + (size_t)row * NN + col;
              outp[idx] = acc[fm][g][r] * inv + wb[row] + pb[row] + x[idx];
          }
      }
}

// ---------------------------------------------------------------------------
extern "C" void kernel_launch(void* const* d_in, const int* in_sizes, int n_in,
                              void* d_out, int out_size, void* d_ws, size_t ws_size,
                              hipStream_t stream)
{
    const float* x   = (const float*)d_in[0];
    const float* gnw = (const float*)d_in[1];
    const float* gnb = (const float*)d_in[2];
    const float* qw  = (const float*)d_in[3];
    const float* qb  = (const float*)d_in[4];
    const float* kw  = (const float*)d_in[5];
    const float* kb  = (const float*)d_in[6];
    const float* vw  = (const float*)d_in[7];
    const float* vb  = (const float*)d_in[8];
    const float* pw  = (const float*)d_in[9];
    const float* pb  = (const float*)d_in[10];
    float* outp = (float*)d_out;

    char* ws = (char*)d_ws;
    size_t off = 0;
    auto alloc = [&](size_t bytes) -> char* {
        char* p = ws + off;
        off = (off + bytes + 255) & ~(size_t)255;
        return p;
    };
    const size_t CN = (size_t)CC * NN;
    bf16*  wbf  = (bf16*)alloc(4 * (size_t)CC * CC * sizeof(bf16));   // q,k,vwT,pw
    bf16*  hT   = (bf16*)alloc(2 * CN * sizeof(bf16));                // 8MB
    bf16*  qT   = (bf16*)alloc(2 * CN * sizeof(bf16));                // 8MB
    bf16*  kT   = (bf16*)alloc(2 * CN * sizeof(bf16));                // 8MB
    bf16*  fw   = (bf16*)alloc((size_t)CC * CC * sizeof(bf16));       // 0.5MB
    bf16*  Wt   = (bf16*)alloc(2 * CN * sizeof(bf16));                // 8MB
    bf16*  E    = (bf16*)alloc(2 * (size_t)NN * NN * sizeof(bf16));   // 64MB
    float* rowsum = (float*)alloc(2 * NN * sizeof(float));            // 32KB
    float* wb   = (float*)alloc(CC * sizeof(float));
    float* mr   = (float*)alloc(64 * 2 * sizeof(float));

    bf16* vwT = wbf + 2 * (size_t)CC * CC;
    bf16* pwb = wbf + 3 * (size_t)CC * CC;

    convert_w_kernel<<<dim3(256, 3), 256, 0, stream>>>(qw, kw, pw, wbf);
    vwT_kernel<<<dim3(8, 8), 256, 0, stream>>>(vw, vwT);
    wb_kernel<<<2, 256, 0, stream>>>(pw, vb, wb);
    hipMemsetAsync(mr, 0, 64 * 2 * sizeof(float), stream);
    gn_stats_kernel<<<256, 256, 0, stream>>>(x, mr);
    gn_apply_T_kernel<<<dim3(NN / 64, CC / 64, 2), 256, 0, stream>>>(
        x, gnw, gnb, mr, hT);
    hipMemsetAsync(rowsum, 0, 2 * NN * sizeof(float), stream);

    fw_gemm_kernel<<<dim3(4, 4), 256, 0, stream>>>(pwb, vwT, fw);
    qkw_gemm_kernel<<<768, 256, 0, stream>>>(
        hT, wbf, fw, qb, kb, qT, kT, Wt);

    se8_kernel<<<dim3(16, 16, 2), 512, 0, stream>>>(qT, kT, E, rowsum);

    pvproj_kernel<<<dim3(NN / BN, 8, 2), 256, 0, stream>>>(
        Wt, E, rowsum, wb, pb, x, outp);
}